// Round 1
// baseline (442.919 us; speedup 1.0000x reference)
//
#include <hip/hip_runtime.h>

#define Bn 16
#define Nn 4096
#define Hn 512
#define Mn 512   // REL_TOKENS
#define NHn 8
#define DHn 64

typedef unsigned short u16;
typedef unsigned int u32;
typedef __attribute__((ext_vector_type(4))) float f32x4;
typedef __attribute__((ext_vector_type(8))) short short8;

__device__ __forceinline__ u16 f2bf(float f){
  u32 u = __float_as_uint(f);
  u32 r = (u + 0x7fffu + ((u >> 16) & 1u)) >> 16;   // RTNE
  return (u16)r;
}

// ---------------- consts: cgw = sum(g*w), cbw = sum(b*w) + sal_b ----------------
__global__ void k_consts(const float* __restrict__ g, const float* __restrict__ bv,
                         const float* __restrict__ w, const float* __restrict__ salb,
                         float* __restrict__ consts){
  int t = threadIdx.x; // 512
  float vg = g[t]*w[t], vb = bv[t]*w[t];
  #pragma unroll
  for (int off=32; off; off>>=1){ vg += __shfl_down(vg,off); vb += __shfl_down(vb,off); }
  __shared__ float sg[8], sb[8];
  int wv = t>>6, lane = t&63;
  if (lane==0){ sg[wv]=vg; sb[wv]=vb; }
  __syncthreads();
  if (t==0){
    float a=0.f, c=0.f;
    for (int i=0;i<8;i++){ a+=sg[i]; c+=sb[i]; }
    consts[0]=a; consts[1]=c + salb[0];
  }
}

// ---------------- pooled column sums ----------------
__global__ __launch_bounds__(256) void k_pooled(const float* __restrict__ tokens, float* __restrict__ pooled){
  int b = blockIdx.x;
  int h = blockIdx.y*256 + threadIdx.x;
  int n0 = blockIdx.z*128;
  const float* p = tokens + ((size_t)b*Nn + n0)*Hn + h;
  float s = 0.f;
  #pragma unroll 4
  for (int i=0;i<128;i++) s += p[(size_t)i*Hn];
  atomicAdd(&pooled[b*Hn+h], s);
}

// ---------------- gate ----------------
__global__ void k_gate(const float* __restrict__ pooled, const float* __restrict__ g,
                       const float* __restrict__ bv, const float* __restrict__ w,
                       const float* __restrict__ gb, float* __restrict__ gate){
  int b = blockIdx.x, t = threadIdx.x; // 512
  float x = pooled[b*Hn+t] * (1.0f/(float)Nn);
  __shared__ float s1[8], s2[8], s3[8];
  float vx = x, vxx = x*x;
  #pragma unroll
  for (int off=32; off; off>>=1){ vx += __shfl_down(vx,off); vxx += __shfl_down(vxx,off); }
  int wv = t>>6, lane = t&63;
  if (lane==0){ s1[wv]=vx; s2[wv]=vxx; }
  __syncthreads();
  float sx=0.f, sxx=0.f;
  for (int i=0;i<8;i++){ sx+=s1[i]; sxx+=s2[i]; }
  float m = sx*(1.f/Hn), v = sxx*(1.f/Hn) - m*m;
  float rs = rsqrtf(v + 1e-5f);
  float y = (x-m)*rs*g[t] + bv[t];
  float d = y*w[t];
  #pragma unroll
  for (int off=32; off; off>>=1) d += __shfl_down(d,off);
  if (lane==0) s3[wv]=d;
  __syncthreads();
  if (t==0){
    float dd=0.f; for (int i=0;i<8;i++) dd+=s3[i];
    dd += gb[0];
    gate[b] = 1.f/(1.f+__expf(-dd));
  }
}

// ---------------- salience (f64 accum: ranking precision) ----------------
__global__ __launch_bounds__(256) void k_salience(const float* __restrict__ tokens,
    const float* __restrict__ g, const float* __restrict__ w,
    const float* __restrict__ consts, float* __restrict__ salience){
  const int wv = threadIdx.x >> 6, lane = threadIdx.x & 63;
  const int row = blockIdx.x*4 + wv;   // b*N + n
  const float* x = tokens + (size_t)row*Hn + lane*8;
  float4 a0 = *(const float4*)x;
  float4 a1 = *(const float4*)(x+4);
  const int h = lane*8;
  float4 g0 = *(const float4*)(g+h), g1 = *(const float4*)(g+h+4);
  float4 w0 = *(const float4*)(w+h), w1 = *(const float4*)(w+h+4);
  float xs[8] = {a0.x,a0.y,a0.z,a0.w,a1.x,a1.y,a1.z,a1.w};
  float gw[8] = {g0.x*w0.x, g0.y*w0.y, g0.z*w0.z, g0.w*w0.w,
                 g1.x*w1.x, g1.y*w1.y, g1.z*w1.z, g1.w*w1.w};
  double sx=0.0, sxx=0.0, sgw=0.0;
  #pragma unroll
  for (int j=0;j<8;j++){ double xv = (double)xs[j]; sx += xv; sxx += xv*xv; sgw += xv*(double)gw[j]; }
  #pragma unroll
  for (int off=32; off; off>>=1){
    sx += __shfl_xor(sx,off); sxx += __shfl_xor(sxx,off); sgw += __shfl_xor(sgw,off);
  }
  if (lane==0){
    double m = sx*(1.0/512.0);
    double v = sxx*(1.0/512.0) - m*m;
    double rs = 1.0/sqrt(v + 1e-5);
    salience[row] = (float)(rs*(sgw - m*(double)consts[0]) + (double)consts[1]);
  }
}

// ---------------- top-512 radix select per batch ----------------
__global__ __launch_bounds__(1024) void k_topk(const float* __restrict__ salience,
                                               int* __restrict__ sal_idx, int* __restrict__ rel_pos){
  const int b = blockIdx.x, t = threadIdx.x;
  __shared__ u32 keys[Nn];
  __shared__ int cnt, csel, ceq;
  for (int i=t;i<Nn;i+=1024){
    u32 u = __float_as_uint(salience[b*Nn+i]);
    u = (u & 0x80000000u) ? ~u : (u | 0x80000000u);
    keys[i] = u;
  }
  if (t==0) cnt = 0;
  __syncthreads();
  u32 prefix = 0, mask = 0;
  int k = Mn;
  for (int bit=31; bit>=0; --bit){
    u32 bm = 1u<<bit;
    u32 want = prefix | bm, m2 = mask | bm;
    int local = 0;
    for (int i=t;i<Nn;i+=1024) local += ((keys[i] & m2) == want) ? 1 : 0;
    #pragma unroll
    for (int off=32; off; off>>=1) local += __shfl_down(local, off);
    if ((t&63)==0 && local) atomicAdd(&cnt, local);
    __syncthreads();
    int c = cnt;
    __syncthreads();
    if (t==0) cnt = 0;
    if (c >= k) prefix |= bm; else k -= c;
    mask = m2;
    __syncthreads();
  }
  if (t==0){ csel=0; ceq=0; }
  __syncthreads();
  for (int i=t;i<Nn;i+=1024){
    u32 u = keys[i];
    int slot = -1;
    if (u > prefix) slot = atomicAdd(&csel,1);
    else if (u == prefix){ int e = atomicAdd(&ceq,1); if (e < k) slot = atomicAdd(&csel,1); }
    if (slot >= 0){ sal_idx[b*Mn+slot] = i; rel_pos[b*Nn+i] = slot; }
  }
}

// ---------------- gather selected rows -> bf16 ----------------
__global__ __launch_bounds__(128) void k_gather(const float* __restrict__ tokens,
                                                const int* __restrict__ sal_idx, u16* __restrict__ sel){
  int r = blockIdx.x;      // b*512+m
  int b = r >> 9;
  int idx = sal_idx[r];
  const float* src = tokens + ((size_t)b*Nn + idx)*Hn + threadIdx.x*4;
  float4 v = *(const float4*)src;
  u16 o[4] = {f2bf(v.x), f2bf(v.y), f2bf(v.z), f2bf(v.w)};
  *(ushort4*)(sel + (size_t)r*Hn + threadIdx.x*4) = *(ushort4*)o;
}

// ---------------- f32 -> bf16 weight convert ----------------
__global__ __launch_bounds__(256) void k_convert(const float* __restrict__ src, u16* __restrict__ dst, int n){
  int i = (blockIdx.x*256 + threadIdx.x)*4;
  if (i < n){
    float4 v = *(const float4*)(src+i);
    u16 o[4] = {f2bf(v.x), f2bf(v.y), f2bf(v.z), f2bf(v.w)};
    *(ushort4*)(dst+i) = *(ushort4*)o;
  }
}

// ---------------- bf16 MFMA GEMM: C[M,N] = A[M,K] * B[N,K]^T + bias ----------------
template<int OUTBF>
__global__ __launch_bounds__(256) void k_gemm(const u16* __restrict__ A, const u16* __restrict__ Bw,
                                              const float* __restrict__ bias, void* __restrict__ Cptr,
                                              int M, int Nc, int K){
  __shared__ u16 As[128][40];   // +8 pad: conflict-free-ish frag reads, 16B-aligned rows
  __shared__ u16 Bs[128][40];
  const int t = threadIdx.x, lane = t&63, w = t>>6;
  const int m0 = blockIdx.y*128, n0 = blockIdx.x*128;
  const int wr = (w>>1)*64, wc = (w&1)*64;
  f32x4 acc[4][4];
  #pragma unroll
  for (int i=0;i<4;i++)
    #pragma unroll
    for (int j=0;j<4;j++) acc[i][j] = (f32x4){0.f,0.f,0.f,0.f};
  const int srow = t>>1, scol = (t&1)*16;
  const u16* Ag = A + (size_t)(m0+srow)*K + scol;
  const u16* Bg = Bw + (size_t)(n0+srow)*K + scol;
  for (int k0=0;k0<K;k0+=32){
    uint4 a0 = *(const uint4*)(Ag+k0); uint4 a1 = *(const uint4*)(Ag+k0+8);
    uint4 b0 = *(const uint4*)(Bg+k0); uint4 b1 = *(const uint4*)(Bg+k0+8);
    __syncthreads();
    *(uint4*)&As[srow][scol] = a0; *(uint4*)&As[srow][scol+8] = a1;
    *(uint4*)&Bs[srow][scol] = b0; *(uint4*)&Bs[srow][scol+8] = b1;
    __syncthreads();
    short8 af[4], bfr[4];
    #pragma unroll
    for (int f=0;f<4;f++) af[f]  = *(const short8*)&As[wr + f*16 + (lane&15)][(lane>>4)*8];
    #pragma unroll
    for (int f=0;f<4;f++) bfr[f] = *(const short8*)&Bs[wc + f*16 + (lane&15)][(lane>>4)*8];
    #pragma unroll
    for (int i=0;i<4;i++)
      #pragma unroll
      for (int j=0;j<4;j++)
        acc[i][j] = __builtin_amdgcn_mfma_f32_16x16x32_bf16(af[i], bfr[j], acc[i][j], 0,0,0);
  }
  const int r0 = (lane>>4)*4, c0 = lane&15;
  #pragma unroll
  for (int i=0;i<4;i++)
    #pragma unroll
    for (int j=0;j<4;j++){
      int col = n0 + wc + j*16 + c0;
      float bc = bias[col];
      #pragma unroll
      for (int r=0;r<4;r++){
        int row = m0 + wr + i*16 + r0 + r;
        float v = acc[i][j][r] + bc;
        if (OUTBF) ((u16*)Cptr)[(size_t)row*Nc + col] = f2bf(v);
        else ((float*)Cptr)[(size_t)row*Nc + col] = v;
      }
    }
}

// ---------------- flash attention: qkv bf16 [8192][1536] -> attn bf16 [8192][512] ----------------
__global__ __launch_bounds__(256) void k_attn(const u16* __restrict__ qkv, u16* __restrict__ attn){
  const int qt = blockIdx.x, h = blockIdx.y, b = blockIdx.z;
  const int t = threadIdx.x, lane = t & 63, w = t >> 6;
  __shared__ u16 Qs[64][72], Ks[64][72], Vs[64][72], Ps[64][72];
  { // load Q tile (64x64)
    int r = t >> 2, cc = (t & 3) * 16;
    const u16* src = qkv + ((size_t)(b*Mn + qt*64 + r))*1536 + h*DHn + cc;
    uint4 v0 = *(const uint4*)src;
    uint4 v1 = *(const uint4*)(src + 8);
    *(uint4*)&Qs[r][cc] = v0;
    *(uint4*)&Qs[r][cc+8] = v1;
  }
  __syncthreads();
  const int wr = w*16;
  short8 aq[2];
  aq[0] = *(const short8*)&Qs[wr + (lane&15)][(lane>>4)*8];
  aq[1] = *(const short8*)&Qs[wr + (lane&15)][32 + (lane>>4)*8];
  f32x4 o[4];
  float m_run[4], l_run[4];
  #pragma unroll
  for (int c=0;c<4;c++) o[c] = (f32x4){0.f,0.f,0.f,0.f};
  #pragma unroll
  for (int r=0;r<4;r++){ m_run[r] = -1e30f; l_run[r] = 0.f; }

  for (int kt=0; kt<8; ++kt){
    __syncthreads();  // prev iteration's reads of Ks/Vs/Ps done
    { // load K tile + V tile (transposed)
      int r = t >> 2, cc = (t&3)*16;
      const u16* srcK = qkv + ((size_t)(b*Mn + kt*64 + r))*1536 + Hn + h*DHn + cc;
      uint4 kk0 = *(const uint4*)srcK, kk1 = *(const uint4*)(srcK+8);
      *(uint4*)&Ks[r][cc] = kk0; *(uint4*)&Ks[r][cc+8] = kk1;
      const u16* srcV = qkv + ((size_t)(b*Mn + kt*64 + r))*1536 + 2*Hn + h*DHn + cc;
      uint4 vv0 = *(const uint4*)srcV, vv1 = *(const uint4*)(srcV+8);
      u16 tmp[16];
      *(uint4*)tmp = vv0; *(uint4*)(tmp+8) = vv1;
      #pragma unroll
      for (int j=0;j<16;j++) Vs[cc+j][r] = tmp[j];
    }
    __syncthreads();
    // S = (Q K^T) / 8
    f32x4 s[4];
    #pragma unroll
    for (int ct=0;ct<4;ct++){
      s[ct] = (f32x4){0.f,0.f,0.f,0.f};
      short8 bk0 = *(const short8*)&Ks[ct*16 + (lane&15)][(lane>>4)*8];
      short8 bk1 = *(const short8*)&Ks[ct*16 + (lane&15)][32+(lane>>4)*8];
      s[ct] = __builtin_amdgcn_mfma_f32_16x16x32_bf16(aq[0], bk0, s[ct], 0,0,0);
      s[ct] = __builtin_amdgcn_mfma_f32_16x16x32_bf16(aq[1], bk1, s[ct], 0,0,0);
      s[ct] = s[ct] * 0.125f;
    }
    // online softmax
    float mx[4];
    #pragma unroll
    for (int r=0;r<4;r++) mx[r] = fmaxf(fmaxf(s[0][r], s[1][r]), fmaxf(s[2][r], s[3][r]));
    #pragma unroll
    for (int off=1; off<16; off<<=1)
      #pragma unroll
      for (int r=0;r<4;r++) mx[r] = fmaxf(mx[r], __shfl_xor(mx[r], off));
    float al[4];
    #pragma unroll
    for (int r=0;r<4;r++){
      float mn = fmaxf(m_run[r], mx[r]);
      al[r] = __expf(m_run[r] - mn);
      m_run[r] = mn;
    }
    float rsum[4] = {0.f,0.f,0.f,0.f};
    #pragma unroll
    for (int ct=0;ct<4;ct++)
      #pragma unroll
      for (int r=0;r<4;r++){
        float p = __expf(s[ct][r] - m_run[r]);
        s[ct][r] = p;
        rsum[r] += p;
      }
    #pragma unroll
    for (int off=1; off<16; off<<=1)
      #pragma unroll
      for (int r=0;r<4;r++) rsum[r] += __shfl_xor(rsum[r], off);
    #pragma unroll
    for (int r=0;r<4;r++) l_run[r] = l_run[r]*al[r] + rsum[r];
    #pragma unroll
    for (int ct=0;ct<4;ct++)
      #pragma unroll
      for (int r=0;r<4;r++) o[ct][r] *= al[r];
    // stage P (wave-private stripe)
    #pragma unroll
    for (int ct=0;ct<4;ct++)
      #pragma unroll
      for (int r=0;r<4;r++)
        Ps[wr + (lane>>4)*4 + r][ct*16 + (lane&15)] = f2bf(s[ct][r]);
    __syncthreads();
    // O += P V
    #pragma unroll
    for (int ct=0;ct<4;ct++)
      #pragma unroll
      for (int ks=0;ks<2;ks++){
        short8 ap = *(const short8*)&Ps[wr + (lane&15)][ks*32 + (lane>>4)*8];
        short8 bv = *(const short8*)&Vs[ct*16 + (lane&15)][ks*32 + (lane>>4)*8];
        o[ct] = __builtin_amdgcn_mfma_f32_16x16x32_bf16(ap, bv, o[ct], 0,0,0);
      }
  }
  float inv[4];
  #pragma unroll
  for (int r=0;r<4;r++) inv[r] = 1.0f / l_run[r];
  #pragma unroll
  for (int ct=0;ct<4;ct++)
    #pragma unroll
    for (int r=0;r<4;r++){
      int grow = b*Mn + qt*64 + wr + (lane>>4)*4 + r;
      int gcol = h*DHn + ct*16 + (lane&15);
      attn[(size_t)grow*Hn + gcol] = f2bf(o[ct][r]*inv[r]);
    }
}

// ---------------- final: out = tokens + gate * scatter(LN(selected + proj)) ----------------
__global__ __launch_bounds__(256) void k_final(const float* __restrict__ tokens,
    const float* __restrict__ proj, const int* __restrict__ rel_pos,
    const float* __restrict__ gate, const float* __restrict__ rg, const float* __restrict__ rb,
    float* __restrict__ out){
  const int wv = threadIdx.x >> 6, lane = threadIdx.x & 63;
  const int row = blockIdx.x*4 + wv;   // b*N + n
  const int b = row >> 12;
  const size_t base = (size_t)row*Hn + lane*8;
  float4 t0 = *(const float4*)(tokens+base);
  float4 t1 = *(const float4*)(tokens+base+4);
  float ov[8] = {t0.x,t0.y,t0.z,t0.w,t1.x,t1.y,t1.z,t1.w};
  const int pos = rel_pos[row];
  if (pos >= 0){
    const float* pr = proj + ((size_t)(b*Mn+pos))*Hn + lane*8;
    float4 p0 = *(const float4*)pr, p1 = *(const float4*)(pr+4);
    float pv[8] = {p0.x,p0.y,p0.z,p0.w,p1.x,p1.y,p1.z,p1.w};
    float sv[8];
    float sx=0.f, sxx=0.f;
    #pragma unroll
    for (int j=0;j<8;j++){ sv[j] = ov[j] + pv[j]; sx += sv[j]; sxx += sv[j]*sv[j]; }
    #pragma unroll
    for (int off=32; off; off>>=1){ sx += __shfl_xor(sx,off); sxx += __shfl_xor(sxx,off); }
    float m = sx*(1.f/Hn), v = sxx*(1.f/Hn) - m*m;
    float rs = rsqrtf(v + 1e-5f);
    int h = lane*8;
    float4 G0 = *(const float4*)(rg+h), G1 = *(const float4*)(rg+h+4);
    float4 B0 = *(const float4*)(rb+h), B1 = *(const float4*)(rb+h+4);
    float gg[8]={G0.x,G0.y,G0.z,G0.w,G1.x,G1.y,G1.z,G1.w};
    float bb[8]={B0.x,B0.y,B0.z,B0.w,B1.x,B1.y,B1.z,B1.w};
    float gt = gate[b];
    #pragma unroll
    for (int j=0;j<8;j++) ov[j] += gt * ((sv[j]-m)*rs*gg[j] + bb[j]);
  }
  float4 o0 = {ov[0],ov[1],ov[2],ov[3]};
  float4 o1 = {ov[4],ov[5],ov[6],ov[7]};
  *(float4*)(out+base) = o0;
  *(float4*)(out+base+4) = o1;
}

// ---------------- workspace layout (bytes) ----------------
#define OFF_POOLED  ((size_t)0)            // 16*512*4 = 32768
#define OFF_GATE    ((size_t)32768)        // 64 -> 256
#define OFF_CONSTS  ((size_t)33024)        // 8 -> 256
#define OFF_SAL     ((size_t)33280)        // 65536*4 = 262144
#define OFF_IDX     ((size_t)295424)       // 8192*4 = 32768
#define OFF_POS     ((size_t)328192)       // 65536*4 = 262144
#define OFF_SELB    ((size_t)590336)       // 8192*512*2 = 8388608
#define OFF_WIN     ((size_t)8978944)      // 1536*512*2 = 1572864
#define OFF_WOUT    ((size_t)10551808)     // 512*512*2 = 524288
#define OFF_QKV     ((size_t)11076096)     // 8192*1536*2 = 25165824
#define OFF_ATTN    ((size_t)36241920)     // 8192*512*2 = 8388608
#define OFF_PROJ    ((size_t)44630528)     // 8192*512*4 = 16777216  (end ~61.4MB)

extern "C" void kernel_launch(void* const* d_in, const int* in_sizes, int n_in,
                              void* d_out, int out_size, void* d_ws, size_t ws_size,
                              hipStream_t stream) {
  const float* tokens    = (const float*)d_in[0];
  const float* gate_ln_g = (const float*)d_in[1];
  const float* gate_ln_b = (const float*)d_in[2];
  const float* gate_w    = (const float*)d_in[3];
  const float* gate_b    = (const float*)d_in[4];
  const float* sal_ln_g  = (const float*)d_in[5];
  const float* sal_ln_b  = (const float*)d_in[6];
  const float* sal_w     = (const float*)d_in[7];
  const float* sal_b     = (const float*)d_in[8];
  const float* in_proj_w = (const float*)d_in[9];
  const float* in_proj_b = (const float*)d_in[10];
  const float* out_proj_w= (const float*)d_in[11];
  const float* out_proj_b= (const float*)d_in[12];
  const float* rel_ln_g  = (const float*)d_in[13];
  const float* rel_ln_b  = (const float*)d_in[14];
  float* out = (float*)d_out;
  char* ws = (char*)d_ws;

  float* pooled  = (float*)(ws + OFF_POOLED);
  float* gate    = (float*)(ws + OFF_GATE);
  float* consts  = (float*)(ws + OFF_CONSTS);
  float* sal     = (float*)(ws + OFF_SAL);
  int*   sal_idx = (int*)  (ws + OFF_IDX);
  int*   rel_pos = (int*)  (ws + OFF_POS);
  u16*   sel_b   = (u16*)  (ws + OFF_SELB);
  u16*   w_in_b  = (u16*)  (ws + OFF_WIN);
  u16*   w_out_b = (u16*)  (ws + OFF_WOUT);
  u16*   qkv     = (u16*)  (ws + OFF_QKV);
  u16*   attnb   = (u16*)  (ws + OFF_ATTN);
  float* proj    = (float*)(ws + OFF_PROJ);

  hipMemsetAsync(pooled, 0, Bn*Hn*sizeof(float), stream);
  hipMemsetAsync(rel_pos, 0xFF, Bn*Nn*sizeof(int), stream);

  k_consts<<<1, 512, 0, stream>>>(sal_ln_g, sal_ln_b, sal_w, sal_b, consts);
  k_pooled<<<dim3(Bn,2,32), 256, 0, stream>>>(tokens, pooled);
  k_salience<<<(Bn*Nn)/4, 256, 0, stream>>>(tokens, sal_ln_g, sal_w, consts, sal);
  k_gate<<<Bn, 512, 0, stream>>>(pooled, gate_ln_g, gate_ln_b, gate_w, gate_b, gate);
  k_topk<<<Bn, 1024, 0, stream>>>(sal, sal_idx, rel_pos);
  k_gather<<<Bn*Mn, 128, 0, stream>>>(tokens, sal_idx, sel_b);
  k_convert<<<768, 256, 0, stream>>>(in_proj_w, w_in_b, 3*Hn*Hn);
  k_convert<<<256, 256, 0, stream>>>(out_proj_w, w_out_b, Hn*Hn);
  // qkv = sel @ in_proj_w^T + b : M=8192, N=1536, K=512
  k_gemm<1><<<dim3(12, 64), 256, 0, stream>>>(sel_b, w_in_b, in_proj_b, qkv, Bn*Mn, 3*Hn, Hn);
  k_attn<<<dim3(8, NHn, Bn), 256, 0, stream>>>(qkv, attnb);
  // proj = attn @ out_proj_w^T + b : M=8192, N=512, K=512
  k_gemm<0><<<dim3(4, 64), 256, 0, stream>>>(attnb, w_out_b, out_proj_b, proj, Bn*Mn, Hn, Hn);
  k_final<<<(Bn*Nn)/4, 256, 0, stream>>>(tokens, proj, rel_pos, gate, rel_ln_g, rel_ln_b, out);
}

// Round 2
// 393.737 us; speedup vs baseline: 1.1249x; 1.1249x over previous
//
#include <hip/hip_runtime.h>

#define Bn 16
#define Nn 4096
#define Hn 512
#define Mn 512   // REL_TOKENS
#define NHn 8
#define DHn 64

typedef unsigned short u16;
typedef unsigned int u32;
typedef __attribute__((ext_vector_type(4))) float f32x4;
typedef __attribute__((ext_vector_type(8))) short short8;

__device__ __forceinline__ u16 f2bf(float f){
  u32 u = __float_as_uint(f);
  u32 r = (u + 0x7fffu + ((u >> 16) & 1u)) >> 16;   // RTNE
  return (u16)r;
}

__device__ __forceinline__ void gload16(const void* g, void* l){
  __builtin_amdgcn_global_load_lds((const __attribute__((address_space(1))) void*)g,
                                   (__attribute__((address_space(3))) void*)l, 16, 0, 0);
}

// ---------------- consts: cgw = sum(g*w), cbw = sum(b*w) + sal_b ----------------
__global__ void k_consts(const float* __restrict__ g, const float* __restrict__ bv,
                         const float* __restrict__ w, const float* __restrict__ salb,
                         float* __restrict__ consts){
  int t = threadIdx.x; // 512
  float vg = g[t]*w[t], vb = bv[t]*w[t];
  #pragma unroll
  for (int off=32; off; off>>=1){ vg += __shfl_down(vg,off); vb += __shfl_down(vb,off); }
  __shared__ float sg[8], sb[8];
  int wv = t>>6, lane = t&63;
  if (lane==0){ sg[wv]=vg; sb[wv]=vb; }
  __syncthreads();
  if (t==0){
    float a=0.f, c=0.f;
    for (int i=0;i<8;i++){ a+=sg[i]; c+=sb[i]; }
    consts[0]=a; consts[1]=c + salb[0];
  }
}

// ------- fused: salience (f64 accum) + pooled column partials + rel_pos init -------
__global__ __launch_bounds__(256) void k_salpool(const float* __restrict__ tokens,
    const float* __restrict__ g, const float* __restrict__ w,
    const float* __restrict__ consts, float* __restrict__ salience,
    float* __restrict__ ppart, int* __restrict__ rel_pos){
  const int b = blockIdx.x >> 5;
  const int chunk = blockIdx.x & 31;
  const int n0 = chunk*128;
  const int t = threadIdx.x, lane = t&63, wv = t>>6;
  if (t < 128) rel_pos[b*Nn + n0 + t] = -1;
  const int h = lane*8;
  float4 g0 = *(const float4*)(g+h), g1 = *(const float4*)(g+h+4);
  float4 w0 = *(const float4*)(w+h), w1 = *(const float4*)(w+h+4);
  float gw[8] = {g0.x*w0.x, g0.y*w0.y, g0.z*w0.z, g0.w*w0.w,
                 g1.x*w1.x, g1.y*w1.y, g1.z*w1.z, g1.w*w1.w};
  const double cgw = (double)consts[0];
  const double cbw = (double)consts[1];
  float cs[8] = {0.f,0.f,0.f,0.f,0.f,0.f,0.f,0.f};
  for (int rr=0; rr<32; rr++){
    const int row = b*Nn + n0 + rr*4 + wv;
    const float* x = tokens + (size_t)row*Hn + h;
    float4 a0 = *(const float4*)x;
    float4 a1 = *(const float4*)(x+4);
    float xs[8] = {a0.x,a0.y,a0.z,a0.w,a1.x,a1.y,a1.z,a1.w};
    double sx=0.0, sxx=0.0, sgw=0.0;
    #pragma unroll
    for (int j=0;j<8;j++){
      double xv = (double)xs[j];
      sx += xv; sxx += xv*xv; sgw += xv*(double)gw[j];
      cs[j] += xs[j];
    }
    #pragma unroll
    for (int off=32; off; off>>=1){
      sx += __shfl_xor(sx,off); sxx += __shfl_xor(sxx,off); sgw += __shfl_xor(sgw,off);
    }
    if (lane==0){
      double m = sx*(1.0/512.0);
      double v = sxx*(1.0/512.0) - m*m;
      double rs = 1.0/sqrt(v + 1e-5);
      salience[row] = (float)(rs*(sgw - m*cgw) + cbw);
    }
  }
  __shared__ float cp[4][512];
  #pragma unroll
  for (int j=0;j<8;j++) cp[wv][h+j] = cs[j];
  __syncthreads();
  for (int cc=t; cc<512; cc+=256){
    float s = cp[0][cc]+cp[1][cc]+cp[2][cc]+cp[3][cc];
    ppart[((size_t)b*32+chunk)*512 + cc] = s;
  }
}

// ---------------- gate (reads pooled partials) ----------------
__global__ void k_gate(const float* __restrict__ ppart, const float* __restrict__ g,
                       const float* __restrict__ bv, const float* __restrict__ w,
                       const float* __restrict__ gb, float* __restrict__ gate){
  int b = blockIdx.x, t = threadIdx.x; // 512
  float x = 0.f;
  for (int c=0;c<32;c++) x += ppart[((size_t)b*32+c)*512 + t];
  x *= (1.0f/(float)Nn);
  __shared__ float s1[8], s2[8], s3[8];
  float vx = x, vxx = x*x;
  #pragma unroll
  for (int off=32; off; off>>=1){ vx += __shfl_down(vx,off); vxx += __shfl_down(vxx,off); }
  int wv = t>>6, lane = t&63;
  if (lane==0){ s1[wv]=vx; s2[wv]=vxx; }
  __syncthreads();
  float sx=0.f, sxx=0.f;
  for (int i=0;i<8;i++){ sx+=s1[i]; sxx+=s2[i]; }
  float m = sx*(1.f/Hn), v = sxx*(1.f/Hn) - m*m;
  float rs = rsqrtf(v + 1e-5f);
  float y = (x-m)*rs*g[t] + bv[t];
  float d = y*w[t];
  #pragma unroll
  for (int off=32; off; off>>=1) d += __shfl_down(d,off);
  if (lane==0) s3[wv]=d;
  __syncthreads();
  if (t==0){
    float dd=0.f; for (int i=0;i<8;i++) dd+=s3[i];
    dd += gb[0];
    gate[b] = 1.f/(1.f+__expf(-dd));
  }
}

// ---------------- top-512: 4-pass 8-bit radix select per batch ----------------
__global__ __launch_bounds__(1024) void k_topk(const float* __restrict__ salience,
                                               int* __restrict__ sal_idx, int* __restrict__ rel_pos){
  const int b = blockIdx.x, t = threadIdx.x;
  __shared__ u32 keys[Nn];
  __shared__ int bins[256];
  __shared__ int suf[256];
  __shared__ int sh_d, sh_gt, csel, ceq;
  for (int i=t;i<Nn;i+=1024){
    u32 u = __float_as_uint(salience[b*Nn+i]);
    keys[i] = (u & 0x80000000u) ? ~u : (u | 0x80000000u);
  }
  int k = Mn;
  u32 prefix = 0;
  #pragma unroll
  for (int shift=24; shift>=0; shift-=8){
    if (t<256) bins[t]=0;
    __syncthreads();
    u32 mask_hi = (shift==24) ? 0u : (0xFFFFFFFFu << (shift+8));
    for (int i=t;i<Nn;i+=1024){
      u32 u = keys[i];
      if ((u & mask_hi) == prefix) atomicAdd(&bins[(u>>shift)&255], 1);
    }
    __syncthreads();
    if (t < 64){
      int b0=bins[t*4], b1=bins[t*4+1], b2=bins[t*4+2], b3=bins[t*4+3];
      int s3=b3, s2=b2+s3, s1=b1+s2, s0=b0+s1;
      int tot = s0;
      #pragma unroll
      for (int off=1; off<64; off<<=1){
        int o = __shfl_down(tot, off);
        if (t+off < 64) tot += o;
      }
      int beyond = tot - s0;
      suf[t*4]=s0+beyond; suf[t*4+1]=s1+beyond; suf[t*4+2]=s2+beyond; suf[t*4+3]=s3+beyond;
    }
    __syncthreads();
    if (t<256){
      int ge = suf[t];
      int gt_ = (t==255) ? 0 : suf[t+1];
      if (ge >= k && gt_ < k){ sh_d = t; sh_gt = gt_; }
    }
    __syncthreads();
    prefix |= ((u32)sh_d) << shift;
    k -= sh_gt;
  }
  if (t==0){ csel=0; ceq=0; }
  __syncthreads();
  for (int i=t;i<Nn;i+=1024){
    u32 u = keys[i];
    int slot = -1;
    if (u > prefix) slot = atomicAdd(&csel,1);
    else if (u == prefix){ int e = atomicAdd(&ceq,1); if (e < k) slot = atomicAdd(&csel,1); }
    if (slot >= 0){ sal_idx[b*Mn+slot] = i; rel_pos[b*Nn+i] = slot; }
  }
}

// ---------------- gather selected rows -> bf16 ----------------
__global__ __launch_bounds__(128) void k_gather(const float* __restrict__ tokens,
                                                const int* __restrict__ sal_idx, u16* __restrict__ sel){
  int r = blockIdx.x;      // b*512+m
  int b = r >> 9;
  int idx = sal_idx[r];
  const float* src = tokens + ((size_t)b*Nn + idx)*Hn + threadIdx.x*4;
  float4 v = *(const float4*)src;
  u16 o[4] = {f2bf(v.x), f2bf(v.y), f2bf(v.z), f2bf(v.w)};
  *(ushort4*)(sel + (size_t)r*Hn + threadIdx.x*4) = *(ushort4*)o;
}

// ---------------- f32 -> bf16 weight convert (both weights, one launch) ----------------
__global__ __launch_bounds__(256) void k_convert2(const float* __restrict__ s1, u16* __restrict__ d1, int n1,
                                                  const float* __restrict__ s2, u16* __restrict__ d2, int n2){
  int i = (blockIdx.x*256 + threadIdx.x)*4;
  if (i < n1){
    float4 v = *(const float4*)(s1+i);
    u16 o[4] = {f2bf(v.x), f2bf(v.y), f2bf(v.z), f2bf(v.w)};
    *(ushort4*)(d1+i) = *(ushort4*)o;
  } else {
    int j = i - n1;
    if (j < n2){
      float4 v = *(const float4*)(s2+j);
      u16 o[4] = {f2bf(v.x), f2bf(v.y), f2bf(v.z), f2bf(v.w)};
      *(ushort4*)(d2+j) = *(ushort4*)o;
    }
  }
}

// -------- bf16 MFMA GEMM (m97 structure): C[M,N] = A[M,K]*B[N,K]^T + bias --------
// 128x128 tile, BK=32, linear LDS, global_load_lds width=16, 2 barriers/K-step.
template<int OUTBF>
__global__ __launch_bounds__(256) void k_gemm(const u16* __restrict__ A, const u16* __restrict__ Bw,
                                              const float* __restrict__ bias, void* __restrict__ Cptr,
                                              int M, int Nc, int K){
  __shared__ __align__(16) u16 As[4096];   // [128][32] linear
  __shared__ __align__(16) u16 Bs[4096];
  const int t = threadIdx.x, lane = t&63, w = t>>6;
  const int m0 = blockIdx.y*128, n0 = blockIdx.x*128;
  const int wr = (w>>1)*64, wc = (w&1)*64;
  f32x4 acc[4][4];
  #pragma unroll
  for (int i=0;i<4;i++)
    #pragma unroll
    for (int j=0;j<4;j++) acc[i][j] = (f32x4){0.f,0.f,0.f,0.f};
  const int lrow = lane>>2;          // 0..15
  const int lcol = (lane&3)*8;       // u16 units
  const u16* Ag0 = A  + (size_t)(m0 + w*32 + lrow)*K + lcol;
  const u16* Ag1 = Ag0 + (size_t)16*K;
  const u16* Bg0 = Bw + (size_t)(n0 + w*32 + lrow)*K + lcol;
  const u16* Bg1 = Bg0 + (size_t)16*K;
  u16* Al0 = As + w*1024;            // HW adds lane*16 bytes
  u16* Al1 = As + w*1024 + 512;
  u16* Bl0 = Bs + w*1024;
  u16* Bl1 = Bs + w*1024 + 512;
  const int fr = lane&15, fq = lane>>4;
  for (int k0=0;k0<K;k0+=32){
    __syncthreads();                  // prior MFMA frag reads complete
    gload16(Ag0+k0, Al0); gload16(Ag1+k0, Al1);
    gload16(Bg0+k0, Bl0); gload16(Bg1+k0, Bl1);
    __syncthreads();                  // compiler drains vmcnt before barrier
    short8 af[4], bf[4];
    #pragma unroll
    for (int f=0;f<4;f++) af[f] = *(const short8*)&As[(wr + f*16 + fr)*32 + fq*8];
    #pragma unroll
    for (int f=0;f<4;f++) bf[f] = *(const short8*)&Bs[(wc + f*16 + fr)*32 + fq*8];
    #pragma unroll
    for (int i=0;i<4;i++)
      #pragma unroll
      for (int j=0;j<4;j++)
        acc[i][j] = __builtin_amdgcn_mfma_f32_16x16x32_bf16(af[i], bf[j], acc[i][j], 0,0,0);
  }
  const int r0 = fq*4, c0 = fr;
  #pragma unroll
  for (int i=0;i<4;i++)
    #pragma unroll
    for (int j=0;j<4;j++){
      int col = n0 + wc + j*16 + c0;
      float bc = bias[col];
      #pragma unroll
      for (int r=0;r<4;r++){
        int row = m0 + wr + i*16 + r0 + r;
        float v = acc[i][j][r] + bc;
        if (OUTBF) ((u16*)Cptr)[(size_t)row*Nc + col] = f2bf(v);
        else ((float*)Cptr)[(size_t)row*Nc + col] = v;
      }
    }
}

// ---------------- flash attention: qkv bf16 [8192][1536] -> attn bf16 [8192][512] ----------------
__global__ __launch_bounds__(256) void k_attn(const u16* __restrict__ qkv, u16* __restrict__ attn){
  const int qt = blockIdx.x, h = blockIdx.y, b = blockIdx.z;
  const int t = threadIdx.x, lane = t & 63, w = t >> 6;
  __shared__ u16 Qs[64][72], Ks[64][72], Vs[64][72], Ps[64][72];
  { // load Q tile (64x64)
    int r = t >> 2, cc = (t & 3) * 16;
    const u16* src = qkv + ((size_t)(b*Mn + qt*64 + r))*1536 + h*DHn + cc;
    uint4 v0 = *(const uint4*)src;
    uint4 v1 = *(const uint4*)(src + 8);
    *(uint4*)&Qs[r][cc] = v0;
    *(uint4*)&Qs[r][cc+8] = v1;
  }
  __syncthreads();
  const int wr = w*16;
  short8 aq[2];
  aq[0] = *(const short8*)&Qs[wr + (lane&15)][(lane>>4)*8];
  aq[1] = *(const short8*)&Qs[wr + (lane&15)][32 + (lane>>4)*8];
  f32x4 o[4];
  float m_run[4], l_run[4];
  #pragma unroll
  for (int c=0;c<4;c++) o[c] = (f32x4){0.f,0.f,0.f,0.f};
  #pragma unroll
  for (int r=0;r<4;r++){ m_run[r] = -1e30f; l_run[r] = 0.f; }

  for (int kt=0; kt<8; ++kt){
    __syncthreads();
    { // load K tile + V tile (transposed)
      int r = t >> 2, cc = (t&3)*16;
      const u16* srcK = qkv + ((size_t)(b*Mn + kt*64 + r))*1536 + Hn + h*DHn + cc;
      uint4 kk0 = *(const uint4*)srcK, kk1 = *(const uint4*)(srcK+8);
      *(uint4*)&Ks[r][cc] = kk0; *(uint4*)&Ks[r][cc+8] = kk1;
      const u16* srcV = qkv + ((size_t)(b*Mn + kt*64 + r))*1536 + 2*Hn + h*DHn + cc;
      uint4 vv0 = *(const uint4*)srcV, vv1 = *(const uint4*)(srcV+8);
      u16 tmp[16];
      *(uint4*)tmp = vv0; *(uint4*)(tmp+8) = vv1;
      #pragma unroll
      for (int j=0;j<16;j++) Vs[cc+j][r] = tmp[j];
    }
    __syncthreads();
    f32x4 s[4];
    #pragma unroll
    for (int ct=0;ct<4;ct++){
      s[ct] = (f32x4){0.f,0.f,0.f,0.f};
      short8 bk0 = *(const short8*)&Ks[ct*16 + (lane&15)][(lane>>4)*8];
      short8 bk1 = *(const short8*)&Ks[ct*16 + (lane&15)][32+(lane>>4)*8];
      s[ct] = __builtin_amdgcn_mfma_f32_16x16x32_bf16(aq[0], bk0, s[ct], 0,0,0);
      s[ct] = __builtin_amdgcn_mfma_f32_16x16x32_bf16(aq[1], bk1, s[ct], 0,0,0);
      s[ct] = s[ct] * 0.125f;
    }
    float mx[4];
    #pragma unroll
    for (int r=0;r<4;r++) mx[r] = fmaxf(fmaxf(s[0][r], s[1][r]), fmaxf(s[2][r], s[3][r]));
    #pragma unroll
    for (int off=1; off<16; off<<=1)
      #pragma unroll
      for (int r=0;r<4;r++) mx[r] = fmaxf(mx[r], __shfl_xor(mx[r], off));
    float al[4];
    #pragma unroll
    for (int r=0;r<4;r++){
      float mn = fmaxf(m_run[r], mx[r]);
      al[r] = __expf(m_run[r] - mn);
      m_run[r] = mn;
    }
    float rsum[4] = {0.f,0.f,0.f,0.f};
    #pragma unroll
    for (int ct=0;ct<4;ct++)
      #pragma unroll
      for (int r=0;r<4;r++){
        float p = __expf(s[ct][r] - m_run[r]);
        s[ct][r] = p;
        rsum[r] += p;
      }
    #pragma unroll
    for (int off=1; off<16; off<<=1)
      #pragma unroll
      for (int r=0;r<4;r++) rsum[r] += __shfl_xor(rsum[r], off);
    #pragma unroll
    for (int r=0;r<4;r++) l_run[r] = l_run[r]*al[r] + rsum[r];
    #pragma unroll
    for (int ct=0;ct<4;ct++)
      #pragma unroll
      for (int r=0;r<4;r++) o[ct][r] *= al[r];
    #pragma unroll
    for (int ct=0;ct<4;ct++)
      #pragma unroll
      for (int r=0;r<4;r++)
        Ps[wr + (lane>>4)*4 + r][ct*16 + (lane&15)] = f2bf(s[ct][r]);
    __syncthreads();
    #pragma unroll
    for (int ct=0;ct<4;ct++)
      #pragma unroll
      for (int ks=0;ks<2;ks++){
        short8 ap = *(const short8*)&Ps[wr + (lane&15)][ks*32 + (lane>>4)*8];
        short8 bv = *(const short8*)&Vs[ct*16 + (lane&15)][ks*32 + (lane>>4)*8];
        o[ct] = __builtin_amdgcn_mfma_f32_16x16x32_bf16(ap, bv, o[ct], 0,0,0);
      }
  }
  float inv[4];
  #pragma unroll
  for (int r=0;r<4;r++) inv[r] = 1.0f / l_run[r];
  #pragma unroll
  for (int ct=0;ct<4;ct++)
    #pragma unroll
    for (int r=0;r<4;r++){
      int grow = b*Mn + qt*64 + wr + (lane>>4)*4 + r;
      int gcol = h*DHn + ct*16 + (lane&15);
      attn[(size_t)grow*Hn + gcol] = f2bf(o[ct][r]*inv[r]);
    }
}

// ---------------- final: out = tokens + gate * scatter(LN(selected + proj)) ----------------
__global__ __launch_bounds__(256) void k_final(const float* __restrict__ tokens,
    const float* __restrict__ proj, const int* __restrict__ rel_pos,
    const float* __restrict__ gate, const float* __restrict__ rg, const float* __restrict__ rb,
    float* __restrict__ out){
  const int wv = threadIdx.x >> 6, lane = threadIdx.x & 63;
  const int row = blockIdx.x*4 + wv;   // b*N + n
  const int b = row >> 12;
  const size_t base = (size_t)row*Hn + lane*8;
  float4 t0 = *(const float4*)(tokens+base);
  float4 t1 = *(const float4*)(tokens+base+4);
  float ov[8] = {t0.x,t0.y,t0.z,t0.w,t1.x,t1.y,t1.z,t1.w};
  const int pos = rel_pos[row];
  if (pos >= 0){
    const float* pr = proj + ((size_t)(b*Mn+pos))*Hn + lane*8;
    float4 p0 = *(const float4*)pr, p1 = *(const float4*)(pr+4);
    float pv[8] = {p0.x,p0.y,p0.z,p0.w,p1.x,p1.y,p1.z,p1.w};
    float sv[8];
    float sx=0.f, sxx=0.f;
    #pragma unroll
    for (int j=0;j<8;j++){ sv[j] = ov[j] + pv[j]; sx += sv[j]; sxx += sv[j]*sv[j]; }
    #pragma unroll
    for (int off=32; off; off>>=1){ sx += __shfl_xor(sx,off); sxx += __shfl_xor(sxx,off); }
    float m = sx*(1.f/Hn), v = sxx*(1.f/Hn) - m*m;
    float rs = rsqrtf(v + 1e-5f);
    int h = lane*8;
    float4 G0 = *(const float4*)(rg+h), G1 = *(const float4*)(rg+h+4);
    float4 B0 = *(const float4*)(rb+h), B1 = *(const float4*)(rb+h+4);
    float gg[8]={G0.x,G0.y,G0.z,G0.w,G1.x,G1.y,G1.z,G1.w};
    float bb[8]={B0.x,B0.y,B0.z,B0.w,B1.x,B1.y,B1.z,B1.w};
    float gt = gate[b];
    #pragma unroll
    for (int j=0;j<8;j++) ov[j] += gt * ((sv[j]-m)*rs*gg[j] + bb[j]);
  }
  float4 o0 = {ov[0],ov[1],ov[2],ov[3]};
  float4 o1 = {ov[4],ov[5],ov[6],ov[7]};
  *(float4*)(out+base) = o0;
  *(float4*)(out+base+4) = o1;
}

// ---------------- workspace layout (bytes) ----------------
#define OFF_GATE    ((size_t)32768)        // 64 -> 256
#define OFF_CONSTS  ((size_t)33024)        // 8 -> 256
#define OFF_SAL     ((size_t)33280)        // 65536*4 = 262144
#define OFF_IDX     ((size_t)295424)       // 8192*4 = 32768
#define OFF_POS     ((size_t)328192)       // 65536*4 = 262144
#define OFF_SELB    ((size_t)590336)       // 8192*512*2 = 8388608
#define OFF_WIN     ((size_t)8978944)      // 1536*512*2 = 1572864
#define OFF_WOUT    ((size_t)10551808)     // 512*512*2 = 524288
#define OFF_QKV     ((size_t)11076096)     // 8192*1536*2 = 25165824
#define OFF_ATTN    ((size_t)36241920)     // 8192*512*2 = 8388608
#define OFF_PROJ    ((size_t)44630528)     // 8192*512*4 = 16777216  (end ~61.4MB)
#define OFF_PPART   OFF_PROJ               // 16*32*512*4 = 1MB; dead before gemm2 writes proj

extern "C" void kernel_launch(void* const* d_in, const int* in_sizes, int n_in,
                              void* d_out, int out_size, void* d_ws, size_t ws_size,
                              hipStream_t stream) {
  const float* tokens    = (const float*)d_in[0];
  const float* gate_ln_g = (const float*)d_in[1];
  const float* gate_ln_b = (const float*)d_in[2];
  const float* gate_w    = (const float*)d_in[3];
  const float* gate_b    = (const float*)d_in[4];
  const float* sal_ln_g  = (const float*)d_in[5];
  const float* sal_ln_b  = (const float*)d_in[6];
  const float* sal_w     = (const float*)d_in[7];
  const float* sal_b     = (const float*)d_in[8];
  const float* in_proj_w = (const float*)d_in[9];
  const float* in_proj_b = (const float*)d_in[10];
  const float* out_proj_w= (const float*)d_in[11];
  const float* out_proj_b= (const float*)d_in[12];
  const float* rel_ln_g  = (const float*)d_in[13];
  const float* rel_ln_b  = (const float*)d_in[14];
  float* out = (float*)d_out;
  char* ws = (char*)d_ws;

  float* gate    = (float*)(ws + OFF_GATE);
  float* consts  = (float*)(ws + OFF_CONSTS);
  float* sal     = (float*)(ws + OFF_SAL);
  int*   sal_idx = (int*)  (ws + OFF_IDX);
  int*   rel_pos = (int*)  (ws + OFF_POS);
  u16*   sel_b   = (u16*)  (ws + OFF_SELB);
  u16*   w_in_b  = (u16*)  (ws + OFF_WIN);
  u16*   w_out_b = (u16*)  (ws + OFF_WOUT);
  u16*   qkv     = (u16*)  (ws + OFF_QKV);
  u16*   attnb   = (u16*)  (ws + OFF_ATTN);
  float* proj    = (float*)(ws + OFF_PROJ);
  float* ppart   = (float*)(ws + OFF_PPART);

  k_consts<<<1, 512, 0, stream>>>(sal_ln_g, sal_ln_b, sal_w, sal_b, consts);
  k_convert2<<<1024, 256, 0, stream>>>(in_proj_w, w_in_b, 3*Hn*Hn, out_proj_w, w_out_b, Hn*Hn);
  k_salpool<<<Bn*32, 256, 0, stream>>>(tokens, sal_ln_g, sal_w, consts, sal, ppart, rel_pos);
  k_gate<<<Bn, 512, 0, stream>>>(ppart, gate_ln_g, gate_ln_b, gate_w, gate_b, gate);
  k_topk<<<Bn, 1024, 0, stream>>>(sal, sal_idx, rel_pos);
  k_gather<<<Bn*Mn, 128, 0, stream>>>(tokens, sal_idx, sel_b);
  // qkv = sel @ in_proj_w^T + b : M=8192, N=1536, K=512
  k_gemm<1><<<dim3(12, 64), 256, 0, stream>>>(sel_b, w_in_b, in_proj_b, qkv, Bn*Mn, 3*Hn, Hn);
  k_attn<<<dim3(8, NHn, Bn), 256, 0, stream>>>(qkv, attnb);
  // proj = attn @ out_proj_w^T + b : M=8192, N=512, K=512
  k_gemm<0><<<dim3(4, 64), 256, 0, stream>>>(attnb, w_out_b, out_proj_b, proj, Bn*Mn, Hn, Hn);
  k_final<<<(Bn*Nn)/4, 256, 0, stream>>>(tokens, proj, rel_pos, gate, rel_ln_g, rel_ln_b, out);
}

// Round 3
// 392.541 us; speedup vs baseline: 1.1283x; 1.0030x over previous
//
#include <hip/hip_runtime.h>

#define Bn 16
#define Nn 4096
#define Hn 512
#define Mn 512   // REL_TOKENS
#define NHn 8
#define DHn 64

typedef unsigned short u16;
typedef unsigned int u32;
typedef __attribute__((ext_vector_type(4))) float f32x4;
typedef __attribute__((ext_vector_type(8))) short short8;

__device__ __forceinline__ u16 f2bf(float f){
  u32 u = __float_as_uint(f);
  u32 r = (u + 0x7fffu + ((u >> 16) & 1u)) >> 16;   // RTNE
  return (u16)r;
}

__device__ __forceinline__ void gload16(const void* g, void* l){
  __builtin_amdgcn_global_load_lds((const __attribute__((address_space(1))) void*)g,
                                   (__attribute__((address_space(3))) void*)l, 16, 0, 0);
}

// ---- weight f32->bf16 convert (blocks 0..1023) + salience consts (block 1024) ----
__global__ __launch_bounds__(256) void k_prep(const float* __restrict__ s1, u16* __restrict__ d1, int n1,
                                              const float* __restrict__ s2, u16* __restrict__ d2, int n2,
                                              const float* __restrict__ g, const float* __restrict__ bv,
                                              const float* __restrict__ w, const float* __restrict__ salb,
                                              float* __restrict__ consts){
  if (blockIdx.x == gridDim.x-1){
    int t = threadIdx.x;           // 256 threads, 512 elems -> 2 each
    float vg = 0.f, vb = 0.f;
    #pragma unroll
    for (int j=0;j<2;j++){
      int i = t + j*256;
      vg += g[i]*w[i]; vb += bv[i]*w[i];
    }
    #pragma unroll
    for (int off=32; off; off>>=1){ vg += __shfl_down(vg,off); vb += __shfl_down(vb,off); }
    __shared__ float sg[4], sb[4];
    int wv = t>>6, lane = t&63;
    if (lane==0){ sg[wv]=vg; sb[wv]=vb; }
    __syncthreads();
    if (t==0){
      float a=0.f, c=0.f;
      for (int i=0;i<4;i++){ a+=sg[i]; c+=sb[i]; }
      consts[0]=a; consts[1]=c + salb[0];
    }
    return;
  }
  int i = (blockIdx.x*256 + threadIdx.x)*4;
  if (i < n1){
    float4 v = *(const float4*)(s1+i);
    u16 o[4] = {f2bf(v.x), f2bf(v.y), f2bf(v.z), f2bf(v.w)};
    *(ushort4*)(d1+i) = *(ushort4*)o;
  } else {
    int j = i - n1;
    if (j < n2){
      float4 v = *(const float4*)(s2+j);
      u16 o[4] = {f2bf(v.x), f2bf(v.y), f2bf(v.z), f2bf(v.w)};
      *(ushort4*)(d2+j) = *(ushort4*)o;
    }
  }
}

// ------- fused: salience (f64 accum) + pooled column partials + rel_pos init -------
__global__ __launch_bounds__(256) void k_salpool(const float* __restrict__ tokens,
    const float* __restrict__ g, const float* __restrict__ w,
    const float* __restrict__ consts, float* __restrict__ salience,
    float* __restrict__ ppart, int* __restrict__ rel_pos){
  const int b = blockIdx.x >> 5;
  const int chunk = blockIdx.x & 31;
  const int n0 = chunk*128;
  const int t = threadIdx.x, lane = t&63, wv = t>>6;
  if (t < 128) rel_pos[b*Nn + n0 + t] = -1;
  const int h = lane*8;
  float4 g0 = *(const float4*)(g+h), g1 = *(const float4*)(g+h+4);
  float4 w0 = *(const float4*)(w+h), w1 = *(const float4*)(w+h+4);
  float gw[8] = {g0.x*w0.x, g0.y*w0.y, g0.z*w0.z, g0.w*w0.w,
                 g1.x*w1.x, g1.y*w1.y, g1.z*w1.z, g1.w*w1.w};
  const double cgw = (double)consts[0];
  const double cbw = (double)consts[1];
  float cs[8] = {0.f,0.f,0.f,0.f,0.f,0.f,0.f,0.f};
  for (int rr=0; rr<32; rr++){
    const int row = b*Nn + n0 + rr*4 + wv;
    const float* x = tokens + (size_t)row*Hn + h;
    float4 a0 = *(const float4*)x;
    float4 a1 = *(const float4*)(x+4);
    float xs[8] = {a0.x,a0.y,a0.z,a0.w,a1.x,a1.y,a1.z,a1.w};
    double sx=0.0, sxx=0.0, sgw=0.0;
    #pragma unroll
    for (int j=0;j<8;j++){
      double xv = (double)xs[j];
      sx += xv; sxx += xv*xv; sgw += xv*(double)gw[j];
      cs[j] += xs[j];
    }
    #pragma unroll
    for (int off=32; off; off>>=1){
      sx += __shfl_xor(sx,off); sxx += __shfl_xor(sxx,off); sgw += __shfl_xor(sgw,off);
    }
    if (lane==0){
      double m = sx*(1.0/512.0);
      double v = sxx*(1.0/512.0) - m*m;
      double rs = 1.0/sqrt(v + 1e-5);
      salience[row] = (float)(rs*(sgw - m*cgw) + cbw);
    }
  }
  __shared__ float cp[4][512];
  #pragma unroll
  for (int j=0;j<8;j++) cp[wv][h+j] = cs[j];
  __syncthreads();
  for (int cc=t; cc<512; cc+=256){
    float s = cp[0][cc]+cp[1][cc]+cp[2][cc]+cp[3][cc];
    ppart[((size_t)b*32+chunk)*512 + cc] = s;
  }
}

// ---------------- gate (reads pooled partials) ----------------
__global__ void k_gate(const float* __restrict__ ppart, const float* __restrict__ g,
                       const float* __restrict__ bv, const float* __restrict__ w,
                       const float* __restrict__ gb, float* __restrict__ gate){
  int b = blockIdx.x, t = threadIdx.x; // 512
  float x = 0.f;
  for (int c=0;c<32;c++) x += ppart[((size_t)b*32+c)*512 + t];
  x *= (1.0f/(float)Nn);
  __shared__ float s1[8], s2[8], s3[8];
  float vx = x, vxx = x*x;
  #pragma unroll
  for (int off=32; off; off>>=1){ vx += __shfl_down(vx,off); vxx += __shfl_down(vxx,off); }
  int wv = t>>6, lane = t&63;
  if (lane==0){ s1[wv]=vx; s2[wv]=vxx; }
  __syncthreads();
  float sx=0.f, sxx=0.f;
  for (int i=0;i<8;i++){ sx+=s1[i]; sxx+=s2[i]; }
  float m = sx*(1.f/Hn), v = sxx*(1.f/Hn) - m*m;
  float rs = rsqrtf(v + 1e-5f);
  float y = (x-m)*rs*g[t] + bv[t];
  float d = y*w[t];
  #pragma unroll
  for (int off=32; off; off>>=1) d += __shfl_down(d,off);
  if (lane==0) s3[wv]=d;
  __syncthreads();
  if (t==0){
    float dd=0.f; for (int i=0;i<8;i++) dd+=s3[i];
    dd += gb[0];
    gate[b] = 1.f/(1.f+__expf(-dd));
  }
}

// ---------------- top-512: 4-pass 8-bit radix select per batch ----------------
__global__ __launch_bounds__(1024) void k_topk(const float* __restrict__ salience,
                                               int* __restrict__ sal_idx, int* __restrict__ rel_pos){
  const int b = blockIdx.x, t = threadIdx.x;
  __shared__ u32 keys[Nn];
  __shared__ int bins[256];
  __shared__ int suf[256];
  __shared__ int sh_d, sh_gt, csel, ceq;
  for (int i=t;i<Nn;i+=1024){
    u32 u = __float_as_uint(salience[b*Nn+i]);
    keys[i] = (u & 0x80000000u) ? ~u : (u | 0x80000000u);
  }
  int k = Mn;
  u32 prefix = 0;
  #pragma unroll
  for (int shift=24; shift>=0; shift-=8){
    if (t<256) bins[t]=0;
    __syncthreads();
    u32 mask_hi = (shift==24) ? 0u : (0xFFFFFFFFu << (shift+8));
    for (int i=t;i<Nn;i+=1024){
      u32 u = keys[i];
      if ((u & mask_hi) == prefix) atomicAdd(&bins[(u>>shift)&255], 1);
    }
    __syncthreads();
    if (t < 64){
      int b0=bins[t*4], b1=bins[t*4+1], b2=bins[t*4+2], b3=bins[t*4+3];
      int s3=b3, s2=b2+s3, s1=b1+s2, s0=b0+s1;
      int tot = s0;
      #pragma unroll
      for (int off=1; off<64; off<<=1){
        int o = __shfl_down(tot, off);
        if (t+off < 64) tot += o;
      }
      int beyond = tot - s0;
      suf[t*4]=s0+beyond; suf[t*4+1]=s1+beyond; suf[t*4+2]=s2+beyond; suf[t*4+3]=s3+beyond;
    }
    __syncthreads();
    if (t<256){
      int ge = suf[t];
      int gt_ = (t==255) ? 0 : suf[t+1];
      if (ge >= k && gt_ < k){ sh_d = t; sh_gt = gt_; }
    }
    __syncthreads();
    prefix |= ((u32)sh_d) << shift;
    k -= sh_gt;
  }
  if (t==0){ csel=0; ceq=0; }
  __syncthreads();
  for (int i=t;i<Nn;i+=1024){
    u32 u = keys[i];
    int slot = -1;
    if (u > prefix) slot = atomicAdd(&csel,1);
    else if (u == prefix){ int e = atomicAdd(&ceq,1); if (e < k) slot = atomicAdd(&csel,1); }
    if (slot >= 0){ sal_idx[b*Mn+slot] = i; rel_pos[b*Nn+i] = slot; }
  }
}

// -------- GEMM1 fused with gather: qkv[M,1536] = bf16(tokens[sal_idx]) @ Win^T + bias --------
// A reg-staged from gathered f32 rows (cvt->LDS); B via global_load_lds w16.
__global__ __launch_bounds__(256) void k_gemm_qkv(const float* __restrict__ tokens,
                                                  const int* __restrict__ sal_idx,
                                                  const u16* __restrict__ Bw,
                                                  const float* __restrict__ bias,
                                                  u16* __restrict__ Cptr){
  const int M = Bn*Mn, Nc = 3*Hn, K = Hn;
  __shared__ __align__(16) u16 As[4096];   // [128][32] linear
  __shared__ __align__(16) u16 Bs[4096];
  const int t = threadIdx.x, lane = t&63, w = t>>6;
  const int m0 = blockIdx.y*128, n0 = blockIdx.x*128;
  const int wr = (w>>1)*64, wc = (w&1)*64;
  f32x4 acc[4][4];
  #pragma unroll
  for (int i=0;i<4;i++)
    #pragma unroll
    for (int j=0;j<4;j++) acc[i][j] = (f32x4){0.f,0.f,0.f,0.f};
  // A gather source: row m0+arow -> tokens[b, sal_idx[m0+arow]]
  const int arow = t>>1, acol = (t&1)*16;
  const int grow = m0 + arow;
  const int gb = grow >> 9;
  const int gidx = sal_idx[grow];
  const float* Asrc = tokens + ((size_t)gb*Nn + gidx)*Hn + acol;
  // B staging: global_load_lds
  const int lrow = lane>>2, lcol = (lane&3)*8;
  const u16* Bg0 = Bw + (size_t)(n0 + w*32 + lrow)*K + lcol;
  const u16* Bg1 = Bg0 + (size_t)16*K;
  u16* Bl0 = Bs + w*1024;
  u16* Bl1 = Bs + w*1024 + 512;
  const int fr = lane&15, fq = lane>>4;
  for (int k0=0;k0<K;k0+=32){
    // issue A gathers early (latency hides under barrier+B loads)
    float4 a0 = *(const float4*)(Asrc+k0);
    float4 a1 = *(const float4*)(Asrc+k0+4);
    float4 a2 = *(const float4*)(Asrc+k0+8);
    float4 a3 = *(const float4*)(Asrc+k0+12);
    __syncthreads();                  // prior MFMA frag reads complete
    gload16(Bg0+k0, Bl0); gload16(Bg1+k0, Bl1);
    u16 cv[16] = {f2bf(a0.x),f2bf(a0.y),f2bf(a0.z),f2bf(a0.w),
                  f2bf(a1.x),f2bf(a1.y),f2bf(a1.z),f2bf(a1.w),
                  f2bf(a2.x),f2bf(a2.y),f2bf(a2.z),f2bf(a2.w),
                  f2bf(a3.x),f2bf(a3.y),f2bf(a3.z),f2bf(a3.w)};
    *(uint4*)&As[arow*32 + acol]     = *(uint4*)&cv[0];
    *(uint4*)&As[arow*32 + acol + 8] = *(uint4*)&cv[8];
    __syncthreads();                  // drains vmcnt (gload_lds) + lgkmcnt (ds_write)
    short8 af[4], bf[4];
    #pragma unroll
    for (int f=0;f<4;f++) af[f] = *(const short8*)&As[(wr + f*16 + fr)*32 + fq*8];
    #pragma unroll
    for (int f=0;f<4;f++) bf[f] = *(const short8*)&Bs[(wc + f*16 + fr)*32 + fq*8];
    #pragma unroll
    for (int i=0;i<4;i++)
      #pragma unroll
      for (int j=0;j<4;j++)
        acc[i][j] = __builtin_amdgcn_mfma_f32_16x16x32_bf16(af[i], bf[j], acc[i][j], 0,0,0);
  }
  const int r0 = fq*4, c0 = fr;
  #pragma unroll
  for (int i=0;i<4;i++)
    #pragma unroll
    for (int j=0;j<4;j++){
      int col = n0 + wc + j*16 + c0;
      float bc = bias[col];
      #pragma unroll
      for (int r=0;r<4;r++){
        int row = m0 + wr + i*16 + r0 + r;
        Cptr[(size_t)row*Nc + col] = f2bf(acc[i][j][r] + bc);
      }
    }
}

// -------- bf16 MFMA GEMM (m97 structure): C[M,N] = A[M,K]*B[N,K]^T + bias, f32 out --------
__global__ __launch_bounds__(256) void k_gemm_out(const u16* __restrict__ A, const u16* __restrict__ Bw,
                                                  const float* __restrict__ bias, float* __restrict__ Cptr,
                                                  int M, int Nc, int K){
  __shared__ __align__(16) u16 As[4096];   // [128][32] linear
  __shared__ __align__(16) u16 Bs[4096];
  const int t = threadIdx.x, lane = t&63, w = t>>6;
  const int m0 = blockIdx.y*128, n0 = blockIdx.x*128;
  const int wr = (w>>1)*64, wc = (w&1)*64;
  f32x4 acc[4][4];
  #pragma unroll
  for (int i=0;i<4;i++)
    #pragma unroll
    for (int j=0;j<4;j++) acc[i][j] = (f32x4){0.f,0.f,0.f,0.f};
  const int lrow = lane>>2;          // 0..15
  const int lcol = (lane&3)*8;       // u16 units
  const u16* Ag0 = A  + (size_t)(m0 + w*32 + lrow)*K + lcol;
  const u16* Ag1 = Ag0 + (size_t)16*K;
  const u16* Bg0 = Bw + (size_t)(n0 + w*32 + lrow)*K + lcol;
  const u16* Bg1 = Bg0 + (size_t)16*K;
  u16* Al0 = As + w*1024;            // HW adds lane*16 bytes
  u16* Al1 = As + w*1024 + 512;
  u16* Bl0 = Bs + w*1024;
  u16* Bl1 = Bs + w*1024 + 512;
  const int fr = lane&15, fq = lane>>4;
  for (int k0=0;k0<K;k0+=32){
    __syncthreads();
    gload16(Ag0+k0, Al0); gload16(Ag1+k0, Al1);
    gload16(Bg0+k0, Bl0); gload16(Bg1+k0, Bl1);
    __syncthreads();
    short8 af[4], bf[4];
    #pragma unroll
    for (int f=0;f<4;f++) af[f] = *(const short8*)&As[(wr + f*16 + fr)*32 + fq*8];
    #pragma unroll
    for (int f=0;f<4;f++) bf[f] = *(const short8*)&Bs[(wc + f*16 + fr)*32 + fq*8];
    #pragma unroll
    for (int i=0;i<4;i++)
      #pragma unroll
      for (int j=0;j<4;j++)
        acc[i][j] = __builtin_amdgcn_mfma_f32_16x16x32_bf16(af[i], bf[j], acc[i][j], 0,0,0);
  }
  const int r0 = fq*4, c0 = fr;
  #pragma unroll
  for (int i=0;i<4;i++)
    #pragma unroll
    for (int j=0;j<4;j++){
      int col = n0 + wc + j*16 + c0;
      float bc = bias[col];
      #pragma unroll
      for (int r=0;r<4;r++){
        int row = m0 + wr + i*16 + r0 + r;
        Cptr[(size_t)row*Nc + col] = acc[i][j][r] + bc;
      }
    }
}

// ---------------- flash attention: qkv bf16 [8192][1536] -> attn bf16 [8192][512] ----------------
__global__ __launch_bounds__(256) void k_attn(const u16* __restrict__ qkv, u16* __restrict__ attn){
  const int qt = blockIdx.x, h = blockIdx.y, b = blockIdx.z;
  const int t = threadIdx.x, lane = t & 63, w = t >> 6;
  __shared__ u16 Qs[64][72], Ks[64][72], Vs[64][72], Ps[64][72];
  { // load Q tile (64x64)
    int r = t >> 2, cc = (t & 3) * 16;
    const u16* src = qkv + ((size_t)(b*Mn + qt*64 + r))*1536 + h*DHn + cc;
    uint4 v0 = *(const uint4*)src;
    uint4 v1 = *(const uint4*)(src + 8);
    *(uint4*)&Qs[r][cc] = v0;
    *(uint4*)&Qs[r][cc+8] = v1;
  }
  __syncthreads();
  const int wr = w*16;
  short8 aq[2];
  aq[0] = *(const short8*)&Qs[wr + (lane&15)][(lane>>4)*8];
  aq[1] = *(const short8*)&Qs[wr + (lane&15)][32 + (lane>>4)*8];
  f32x4 o[4];
  float m_run[4], l_run[4];
  #pragma unroll
  for (int c=0;c<4;c++) o[c] = (f32x4){0.f,0.f,0.f,0.f};
  #pragma unroll
  for (int r=0;r<4;r++){ m_run[r] = -1e30f; l_run[r] = 0.f; }

  for (int kt=0; kt<8; ++kt){
    __syncthreads();
    { // load K tile + V tile (transposed)
      int r = t >> 2, cc = (t&3)*16;
      const u16* srcK = qkv + ((size_t)(b*Mn + kt*64 + r))*1536 + Hn + h*DHn + cc;
      uint4 kk0 = *(const uint4*)srcK, kk1 = *(const uint4*)(srcK+8);
      *(uint4*)&Ks[r][cc] = kk0; *(uint4*)&Ks[r][cc+8] = kk1;
      const u16* srcV = qkv + ((size_t)(b*Mn + kt*64 + r))*1536 + 2*Hn + h*DHn + cc;
      uint4 vv0 = *(const uint4*)srcV, vv1 = *(const uint4*)(srcV+8);
      u16 tmp[16];
      *(uint4*)tmp = vv0; *(uint4*)(tmp+8) = vv1;
      #pragma unroll
      for (int j=0;j<16;j++) Vs[cc+j][r] = tmp[j];
    }
    __syncthreads();
    f32x4 s[4];
    __builtin_amdgcn_s_setprio(1);
    #pragma unroll
    for (int ct=0;ct<4;ct++){
      s[ct] = (f32x4){0.f,0.f,0.f,0.f};
      short8 bk0 = *(const short8*)&Ks[ct*16 + (lane&15)][(lane>>4)*8];
      short8 bk1 = *(const short8*)&Ks[ct*16 + (lane&15)][32+(lane>>4)*8];
      s[ct] = __builtin_amdgcn_mfma_f32_16x16x32_bf16(aq[0], bk0, s[ct], 0,0,0);
      s[ct] = __builtin_amdgcn_mfma_f32_16x16x32_bf16(aq[1], bk1, s[ct], 0,0,0);
      s[ct] = s[ct] * 0.125f;
    }
    __builtin_amdgcn_s_setprio(0);
    float mx[4];
    #pragma unroll
    for (int r=0;r<4;r++) mx[r] = fmaxf(fmaxf(s[0][r], s[1][r]), fmaxf(s[2][r], s[3][r]));
    #pragma unroll
    for (int off=1; off<16; off<<=1)
      #pragma unroll
      for (int r=0;r<4;r++) mx[r] = fmaxf(mx[r], __shfl_xor(mx[r], off));
    float al[4];
    #pragma unroll
    for (int r=0;r<4;r++){
      float mn = fmaxf(m_run[r], mx[r]);
      al[r] = __expf(m_run[r] - mn);
      m_run[r] = mn;
    }
    float rsum[4] = {0.f,0.f,0.f,0.f};
    #pragma unroll
    for (int ct=0;ct<4;ct++)
      #pragma unroll
      for (int r=0;r<4;r++){
        float p = __expf(s[ct][r] - m_run[r]);
        s[ct][r] = p;
        rsum[r] += p;
      }
    #pragma unroll
    for (int off=1; off<16; off<<=1)
      #pragma unroll
      for (int r=0;r<4;r++) rsum[r] += __shfl_xor(rsum[r], off);
    #pragma unroll
    for (int r=0;r<4;r++) l_run[r] = l_run[r]*al[r] + rsum[r];
    #pragma unroll
    for (int ct=0;ct<4;ct++)
      #pragma unroll
      for (int r=0;r<4;r++) o[ct][r] *= al[r];
    #pragma unroll
    for (int ct=0;ct<4;ct++)
      #pragma unroll
      for (int r=0;r<4;r++)
        Ps[wr + (lane>>4)*4 + r][ct*16 + (lane&15)] = f2bf(s[ct][r]);
    __syncthreads();
    __builtin_amdgcn_s_setprio(1);
    #pragma unroll
    for (int ct=0;ct<4;ct++)
      #pragma unroll
      for (int ks=0;ks<2;ks++){
        short8 ap = *(const short8*)&Ps[wr + (lane&15)][ks*32 + (lane>>4)*8];
        short8 bv = *(const short8*)&Vs[ct*16 + (lane&15)][ks*32 + (lane>>4)*8];
        o[ct] = __builtin_amdgcn_mfma_f32_16x16x32_bf16(ap, bv, o[ct], 0,0,0);
      }
    __builtin_amdgcn_s_setprio(0);
  }
  float inv[4];
  #pragma unroll
  for (int r=0;r<4;r++) inv[r] = 1.0f / l_run[r];
  #pragma unroll
  for (int ct=0;ct<4;ct++)
    #pragma unroll
    for (int r=0;r<4;r++){
      int grow = b*Mn + qt*64 + wr + (lane>>4)*4 + r;
      int gcol = h*DHn + ct*16 + (lane&15);
      attn[(size_t)grow*Hn + gcol] = f2bf(o[ct][r]*inv[r]);
    }
}

// ---------------- final: out = tokens + gate * scatter(LN(selected + proj)) ----------------
__global__ __launch_bounds__(256) void k_final(const float* __restrict__ tokens,
    const float* __restrict__ proj, const int* __restrict__ rel_pos,
    const float* __restrict__ gate, const float* __restrict__ rg, const float* __restrict__ rb,
    float* __restrict__ out){
  const int wv = threadIdx.x >> 6, lane = threadIdx.x & 63;
  const int row = blockIdx.x*4 + wv;   // b*N + n
  const int b = row >> 12;
  const size_t base = (size_t)row*Hn + lane*8;
  float4 t0 = *(const float4*)(tokens+base);
  float4 t1 = *(const float4*)(tokens+base+4);
  float ov[8] = {t0.x,t0.y,t0.z,t0.w,t1.x,t1.y,t1.z,t1.w};
  const int pos = rel_pos[row];
  if (pos >= 0){
    const float* pr = proj + ((size_t)(b*Mn+pos))*Hn + lane*8;
    float4 p0 = *(const float4*)pr, p1 = *(const float4*)(pr+4);
    float pv[8] = {p0.x,p0.y,p0.z,p0.w,p1.x,p1.y,p1.z,p1.w};
    float sv[8];
    float sx=0.f, sxx=0.f;
    #pragma unroll
    for (int j=0;j<8;j++){ sv[j] = ov[j] + pv[j]; sx += sv[j]; sxx += sv[j]*sv[j]; }
    #pragma unroll
    for (int off=32; off; off>>=1){ sx += __shfl_xor(sx,off); sxx += __shfl_xor(sxx,off); }
    float m = sx*(1.f/Hn), v = sxx*(1.f/Hn) - m*m;
    float rs = rsqrtf(v + 1e-5f);
    int h = lane*8;
    float4 G0 = *(const float4*)(rg+h), G1 = *(const float4*)(rg+h+4);
    float4 B0 = *(const float4*)(rb+h), B1 = *(const float4*)(rb+h+4);
    float gg[8]={G0.x,G0.y,G0.z,G0.w,G1.x,G1.y,G1.z,G1.w};
    float bb[8]={B0.x,B0.y,B0.z,B0.w,B1.x,B1.y,B1.z,B1.w};
    float gt = gate[b];
    #pragma unroll
    for (int j=0;j<8;j++) ov[j] += gt * ((sv[j]-m)*rs*gg[j] + bb[j]);
  }
  float4 o0 = {ov[0],ov[1],ov[2],ov[3]};
  float4 o1 = {ov[4],ov[5],ov[6],ov[7]};
  *(float4*)(out+base) = o0;
  *(float4*)(out+base+4) = o1;
}

// ---------------- workspace layout (bytes) ----------------
#define OFF_GATE    ((size_t)32768)        // 64 -> 256
#define OFF_CONSTS  ((size_t)33024)        // 8 -> 256
#define OFF_SAL     ((size_t)33280)        // 65536*4 = 262144
#define OFF_IDX     ((size_t)295424)       // 8192*4 = 32768
#define OFF_POS     ((size_t)328192)       // 65536*4 = 262144
#define OFF_WIN     ((size_t)8978944)      // 1536*512*2 = 1572864
#define OFF_WOUT    ((size_t)10551808)     // 512*512*2 = 524288
#define OFF_QKV     ((size_t)11076096)     // 8192*1536*2 = 25165824
#define OFF_ATTN    ((size_t)36241920)     // 8192*512*2 = 8388608
#define OFF_PROJ    ((size_t)44630528)     // 8192*512*4 = 16777216  (end ~61.4MB)
#define OFF_PPART   OFF_PROJ               // 16*32*512*4 = 1MB; dead before gemm2 writes proj

extern "C" void kernel_launch(void* const* d_in, const int* in_sizes, int n_in,
                              void* d_out, int out_size, void* d_ws, size_t ws_size,
                              hipStream_t stream) {
  const float* tokens    = (const float*)d_in[0];
  const float* gate_ln_g = (const float*)d_in[1];
  const float* gate_ln_b = (const float*)d_in[2];
  const float* gate_w    = (const float*)d_in[3];
  const float* gate_b    = (const float*)d_in[4];
  const float* sal_ln_g  = (const float*)d_in[5];
  const float* sal_ln_b  = (const float*)d_in[6];
  const float* sal_w     = (const float*)d_in[7];
  const float* sal_b     = (const float*)d_in[8];
  const float* in_proj_w = (const float*)d_in[9];
  const float* in_proj_b = (const float*)d_in[10];
  const float* out_proj_w= (const float*)d_in[11];
  const float* out_proj_b= (const float*)d_in[12];
  const float* rel_ln_g  = (const float*)d_in[13];
  const float* rel_ln_b  = (const float*)d_in[14];
  float* out = (float*)d_out;
  char* ws = (char*)d_ws;

  float* gate    = (float*)(ws + OFF_GATE);
  float* consts  = (float*)(ws + OFF_CONSTS);
  float* sal     = (float*)(ws + OFF_SAL);
  int*   sal_idx = (int*)  (ws + OFF_IDX);
  int*   rel_pos = (int*)  (ws + OFF_POS);
  u16*   w_in_b  = (u16*)  (ws + OFF_WIN);
  u16*   w_out_b = (u16*)  (ws + OFF_WOUT);
  u16*   qkv     = (u16*)  (ws + OFF_QKV);
  u16*   attnb   = (u16*)  (ws + OFF_ATTN);
  float* proj    = (float*)(ws + OFF_PROJ);
  float* ppart   = (float*)(ws + OFF_PPART);

  // weights convert + salience consts (one launch)
  k_prep<<<1025, 256, 0, stream>>>(in_proj_w, w_in_b, 3*Hn*Hn, out_proj_w, w_out_b, Hn*Hn,
                                   sal_ln_g, sal_ln_b, sal_w, sal_b, consts);
  k_salpool<<<Bn*32, 256, 0, stream>>>(tokens, sal_ln_g, sal_w, consts, sal, ppart, rel_pos);
  k_gate<<<Bn, 512, 0, stream>>>(ppart, gate_ln_g, gate_ln_b, gate_w, gate_b, gate);
  k_topk<<<Bn, 1024, 0, stream>>>(sal, sal_idx, rel_pos);
  // qkv = gather(tokens)@Win^T + b : M=8192, N=1536, K=512 (gather fused)
  k_gemm_qkv<<<dim3(12, 64), 256, 0, stream>>>(tokens, sal_idx, w_in_b, in_proj_b, qkv);
  k_attn<<<dim3(8, NHn, Bn), 256, 0, stream>>>(qkv, attnb);
  // proj = attn @ out_proj_w^T + b : M=8192, N=512, K=512
  k_gemm_out<<<dim3(4, 64), 256, 0, stream>>>(attnb, w_out_b, out_proj_b, proj, Bn*Mn, Hn, Hn);
  k_final<<<(Bn*Nn)/4, 256, 0, stream>>>(tokens, proj, rel_pos, gate, rel_ln_g, rel_ln_b, out);
}

// Round 4
// 379.017 us; speedup vs baseline: 1.1686x; 1.0357x over previous
//
#include <hip/hip_runtime.h>

#define Bn 16
#define Nn 4096
#define Hn 512
#define Mn 512   // REL_TOKENS
#define NHn 8
#define DHn 64

typedef unsigned short u16;
typedef unsigned int u32;
typedef __attribute__((ext_vector_type(4))) float f32x4;
typedef __attribute__((ext_vector_type(8))) short short8;

__device__ __forceinline__ u16 f2bf(float f){
  u32 u = __float_as_uint(f);
  u32 r = (u + 0x7fffu + ((u >> 16) & 1u)) >> 16;   // RTNE
  return (u16)r;
}

__device__ __forceinline__ void gload16(const void* g, void* l){
  __builtin_amdgcn_global_load_lds((const __attribute__((address_space(1))) void*)g,
                                   (__attribute__((address_space(3))) void*)l, 16, 0, 0);
}

// ===== fused prep: weight f32->bf16 convert + salience (f64, in-block consts)
//       + pooled column partials + out = tokens copy =====
// grid 512: blk = b*32 + chunk (128 rows per block)
__global__ __launch_bounds__(256) void k_salpool(const float* __restrict__ tokens,
    const float* __restrict__ g, const float* __restrict__ bv,
    const float* __restrict__ w, const float* __restrict__ salb,
    const float* __restrict__ w_in_f, const float* __restrict__ w_out_f,
    u16* __restrict__ w_in_b, u16* __restrict__ w_out_b,
    float* __restrict__ salience, float* __restrict__ ppart, float* __restrict__ out){
  const int blk = blockIdx.x;
  const int b = blk >> 5, chunk = blk & 31, n0 = chunk*128;
  const int t = threadIdx.x, lane = t&63, wv = t>>6;
  // ---- distributed weight convert: this block converts 2048 contiguous f32 ----
  {
    size_t off = (size_t)blk*2048 + (size_t)t*8;
    const float* src = w_in_f; u16* dst = w_in_b;
    if (blk >= 384){ src = w_out_f; dst = w_out_b; off -= (size_t)384*2048; }
    float4 v0 = *(const float4*)(src+off);
    float4 v1 = *(const float4*)(src+off+4);
    u16 o[8] = {f2bf(v0.x),f2bf(v0.y),f2bf(v0.z),f2bf(v0.w),
                f2bf(v1.x),f2bf(v1.y),f2bf(v1.z),f2bf(v1.w)};
    *(ushort4*)(dst+off)   = *(ushort4*)&o[0];
    *(ushort4*)(dst+off+4) = *(ushort4*)&o[4];
  }
  // ---- per-lane LN params + in-block consts ----
  const int h = lane*8;
  float4 g0 = *(const float4*)(g+h), g1 = *(const float4*)(g+h+4);
  float4 w0 = *(const float4*)(w+h), w1 = *(const float4*)(w+h+4);
  float4 b0 = *(const float4*)(bv+h), b1 = *(const float4*)(bv+h+4);
  float gw[8] = {g0.x*w0.x, g0.y*w0.y, g0.z*w0.z, g0.w*w0.w,
                 g1.x*w1.x, g1.y*w1.y, g1.z*w1.z, g1.w*w1.w};
  float cg = gw[0]+gw[1]+gw[2]+gw[3]+gw[4]+gw[5]+gw[6]+gw[7];
  float cb = b0.x*w0.x + b0.y*w0.y + b0.z*w0.z + b0.w*w0.w
           + b1.x*w1.x + b1.y*w1.y + b1.z*w1.z + b1.w*w1.w;
  #pragma unroll
  for (int off=32; off; off>>=1){ cg += __shfl_xor(cg,off); cb += __shfl_xor(cb,off); }
  const double cgw = (double)cg;
  const double cbw = (double)(cb + salb[0]);
  // ---- salience + column partials + out copy ----
  float cs[8] = {0.f,0.f,0.f,0.f,0.f,0.f,0.f,0.f};
  for (int rr=0; rr<32; rr++){
    const int row = b*Nn + n0 + rr*4 + wv;
    const float* x = tokens + (size_t)row*Hn + h;
    float4 a0 = *(const float4*)x;
    float4 a1 = *(const float4*)(x+4);
    float* op = out + (size_t)row*Hn + h;
    *(float4*)op = a0;
    *(float4*)(op+4) = a1;
    float xs[8] = {a0.x,a0.y,a0.z,a0.w,a1.x,a1.y,a1.z,a1.w};
    double sx=0.0, sxx=0.0, sgw=0.0;
    #pragma unroll
    for (int j=0;j<8;j++){
      double xv = (double)xs[j];
      sx += xv; sxx += xv*xv; sgw += xv*(double)gw[j];
      cs[j] += xs[j];
    }
    #pragma unroll
    for (int off=32; off; off>>=1){
      sx += __shfl_xor(sx,off); sxx += __shfl_xor(sxx,off); sgw += __shfl_xor(sgw,off);
    }
    if (lane==0){
      double m = sx*(1.0/512.0);
      double v = sxx*(1.0/512.0) - m*m;
      double rs = 1.0/sqrt(v + 1e-5);
      salience[row] = (float)(rs*(sgw - m*cgw) + cbw);
    }
  }
  __shared__ float cp[4][512];
  #pragma unroll
  for (int j=0;j<8;j++) cp[wv][h+j] = cs[j];
  __syncthreads();
  for (int cc=t; cc<512; cc+=256){
    float s = cp[0][cc]+cp[1][cc]+cp[2][cc]+cp[3][cc];
    ppart[((size_t)b*32+chunk)*512 + cc] = s;
  }
}

// ===== fused gate + top-512 radix select, one block per batch =====
__global__ __launch_bounds__(1024) void k_topkgate(const float* __restrict__ salience,
    int* __restrict__ sal_idx,
    const float* __restrict__ ppart, const float* __restrict__ gg,
    const float* __restrict__ gbln, const float* __restrict__ gw,
    const float* __restrict__ gbias, float* __restrict__ gate){
  const int b = blockIdx.x, t = threadIdx.x;
  const int lane = t&63, wv = t>>6;
  __shared__ u32 keys[Nn];
  __shared__ int bins[256];
  __shared__ int suf[256];
  __shared__ int sh_d, sh_gt, csel, ceq;
  __shared__ float s1[8], s2[8], s3[8];
  // stage keys (all threads) — gate interleaves below
  for (int i=t;i<Nn;i+=1024){
    u32 u = __float_as_uint(salience[b*Nn+i]);
    keys[i] = (u & 0x80000000u) ? ~u : (u | 0x80000000u);
  }
  // ---- gate phase (threads 0..511) ----
  float x = 0.f;
  if (t < 512){
    for (int c=0;c<32;c++) x += ppart[((size_t)b*32+c)*512 + t];
    x *= (1.0f/(float)Nn);
  }
  float vx = x, vxx = x*x;
  #pragma unroll
  for (int off=32; off; off>>=1){ vx += __shfl_down(vx,off); vxx += __shfl_down(vxx,off); }
  if (t < 512 && lane==0){ s1[wv]=vx; s2[wv]=vxx; }
  __syncthreads();
  float d = 0.f;
  if (t < 512){
    float sx=0.f, sxx=0.f;
    for (int i=0;i<8;i++){ sx+=s1[i]; sxx+=s2[i]; }
    float m = sx*(1.f/Hn), v = sxx*(1.f/Hn) - m*m;
    float rs = rsqrtf(v + 1e-5f);
    float y = (x-m)*rs*gg[t] + gbln[t];
    d = y*gw[t];
  }
  #pragma unroll
  for (int off=32; off; off>>=1) d += __shfl_down(d,off);
  if (t < 512 && lane==0) s3[wv]=d;
  __syncthreads();
  if (t==0){
    float dd=0.f; for (int i=0;i<8;i++) dd+=s3[i];
    dd += gbias[0];
    gate[b] = 1.f/(1.f+__expf(-dd));
  }
  // ---- top-k phase: 4-pass 8-bit radix ----
  int k = Mn;
  u32 prefix = 0;
  #pragma unroll
  for (int shift=24; shift>=0; shift-=8){
    if (t<256) bins[t]=0;
    __syncthreads();
    u32 mask_hi = (shift==24) ? 0u : (0xFFFFFFFFu << (shift+8));
    for (int i=t;i<Nn;i+=1024){
      u32 u = keys[i];
      if ((u & mask_hi) == prefix) atomicAdd(&bins[(u>>shift)&255], 1);
    }
    __syncthreads();
    if (t < 64){
      int b0=bins[t*4], b1=bins[t*4+1], b2=bins[t*4+2], b3=bins[t*4+3];
      int q3=b3, q2=b2+q3, q1=b1+q2, q0=b0+q1;
      int tot = q0;
      #pragma unroll
      for (int off=1; off<64; off<<=1){
        int o = __shfl_down(tot, off);
        if (t+off < 64) tot += o;
      }
      int beyond = tot - q0;
      suf[t*4]=q0+beyond; suf[t*4+1]=q1+beyond; suf[t*4+2]=q2+beyond; suf[t*4+3]=q3+beyond;
    }
    __syncthreads();
    if (t<256){
      int ge = suf[t];
      int gt_ = (t==255) ? 0 : suf[t+1];
      if (ge >= k && gt_ < k){ sh_d = t; sh_gt = gt_; }
    }
    __syncthreads();
    prefix |= ((u32)sh_d) << shift;
    k -= sh_gt;
  }
  if (t==0){ csel=0; ceq=0; }
  __syncthreads();
  for (int i=t;i<Nn;i+=1024){
    u32 u = keys[i];
    int slot = -1;
    if (u > prefix) slot = atomicAdd(&csel,1);
    else if (u == prefix){ int e = atomicAdd(&ceq,1); if (e < k) slot = atomicAdd(&csel,1); }
    if (slot >= 0) sal_idx[b*Mn+slot] = i;
  }
}

// ===== GEMM1 fused with gather (pipelined A prefetch):
//       qkv[M,1536] = bf16(tokens[sal_idx]) @ Win^T + bias =====
__global__ __launch_bounds__(256) void k_gemm_qkv(const float* __restrict__ tokens,
                                                  const int* __restrict__ sal_idx,
                                                  const u16* __restrict__ Bw,
                                                  const float* __restrict__ bias,
                                                  u16* __restrict__ Cptr){
  const int Nc = 3*Hn, K = Hn;
  __shared__ __align__(16) u16 As[4096];   // [128][32] linear
  __shared__ __align__(16) u16 Bs[4096];
  const int t = threadIdx.x, lane = t&63, w = t>>6;
  const int m0 = blockIdx.y*128, n0 = blockIdx.x*128;
  const int wr = (w>>1)*64, wc = (w&1)*64;
  f32x4 acc[4][4];
  #pragma unroll
  for (int i=0;i<4;i++)
    #pragma unroll
    for (int j=0;j<4;j++) acc[i][j] = (f32x4){0.f,0.f,0.f,0.f};
  // A gather source: row m0+arow -> tokens[b, sal_idx[m0+arow]]
  const int arow = t>>1, acol = (t&1)*16;
  const int grow = m0 + arow;
  const int gb = grow >> 9;
  const int gidx = sal_idx[grow];
  const float* Asrc = tokens + ((size_t)gb*Nn + gidx)*Hn + acol;
  // B staging: global_load_lds
  const int lrow = lane>>2, lcol = (lane&3)*8;
  const u16* Bg0 = Bw + (size_t)(n0 + w*32 + lrow)*K + lcol;
  const u16* Bg1 = Bg0 + (size_t)16*K;
  u16* Bl0 = Bs + w*1024;
  u16* Bl1 = Bs + w*1024 + 512;
  const int fr = lane&15, fq = lane>>4;
  // prefetch first A chunk
  float4 a0 = *(const float4*)(Asrc);
  float4 a1 = *(const float4*)(Asrc+4);
  float4 a2 = *(const float4*)(Asrc+8);
  float4 a3 = *(const float4*)(Asrc+12);
  for (int k0=0;k0<K;k0+=32){
    __syncthreads();                  // prior frag reads complete
    gload16(Bg0+k0, Bl0); gload16(Bg1+k0, Bl1);
    u16 cv[16] = {f2bf(a0.x),f2bf(a0.y),f2bf(a0.z),f2bf(a0.w),
                  f2bf(a1.x),f2bf(a1.y),f2bf(a1.z),f2bf(a1.w),
                  f2bf(a2.x),f2bf(a2.y),f2bf(a2.z),f2bf(a2.w),
                  f2bf(a3.x),f2bf(a3.y),f2bf(a3.z),f2bf(a3.w)};
    *(uint4*)&As[arow*32 + acol]     = *(uint4*)&cv[0];
    *(uint4*)&As[arow*32 + acol + 8] = *(uint4*)&cv[8];
    __syncthreads();                  // drains gload_lds + ds_write
    // prefetch next A chunk NOW: latency hides under ds_read+MFMA phase
    if (k0+32 < K){
      a0 = *(const float4*)(Asrc+k0+32);
      a1 = *(const float4*)(Asrc+k0+36);
      a2 = *(const float4*)(Asrc+k0+40);
      a3 = *(const float4*)(Asrc+k0+44);
    }
    short8 af[4], bf[4];
    #pragma unroll
    for (int f=0;f<4;f++) af[f] = *(const short8*)&As[(wr + f*16 + fr)*32 + fq*8];
    #pragma unroll
    for (int f=0;f<4;f++) bf[f] = *(const short8*)&Bs[(wc + f*16 + fr)*32 + fq*8];
    #pragma unroll
    for (int i=0;i<4;i++)
      #pragma unroll
      for (int j=0;j<4;j++)
        acc[i][j] = __builtin_amdgcn_mfma_f32_16x16x32_bf16(af[i], bf[j], acc[i][j], 0,0,0);
  }
  const int r0 = fq*4, c0 = fr;
  #pragma unroll
  for (int i=0;i<4;i++)
    #pragma unroll
    for (int j=0;j<4;j++){
      int col = n0 + wc + j*16 + c0;
      float bc = bias[col];
      #pragma unroll
      for (int r=0;r<4;r++){
        int row = m0 + wr + i*16 + r0 + r;
        Cptr[(size_t)row*Nc + col] = f2bf(acc[i][j][r] + bc);
      }
    }
}

// ===== bf16 MFMA GEMM (m97): proj[M,N] = A[M,K]*B[N,K]^T + bias, f32 out =====
__global__ __launch_bounds__(256) void k_gemm_out(const u16* __restrict__ A, const u16* __restrict__ Bw,
                                                  const float* __restrict__ bias, float* __restrict__ Cptr,
                                                  int M, int Nc, int K){
  __shared__ __align__(16) u16 As[4096];
  __shared__ __align__(16) u16 Bs[4096];
  const int t = threadIdx.x, lane = t&63, w = t>>6;
  const int m0 = blockIdx.y*128, n0 = blockIdx.x*128;
  const int wr = (w>>1)*64, wc = (w&1)*64;
  f32x4 acc[4][4];
  #pragma unroll
  for (int i=0;i<4;i++)
    #pragma unroll
    for (int j=0;j<4;j++) acc[i][j] = (f32x4){0.f,0.f,0.f,0.f};
  const int lrow = lane>>2;
  const int lcol = (lane&3)*8;
  const u16* Ag0 = A  + (size_t)(m0 + w*32 + lrow)*K + lcol;
  const u16* Ag1 = Ag0 + (size_t)16*K;
  const u16* Bg0 = Bw + (size_t)(n0 + w*32 + lrow)*K + lcol;
  const u16* Bg1 = Bg0 + (size_t)16*K;
  u16* Al0 = As + w*1024;
  u16* Al1 = As + w*1024 + 512;
  u16* Bl0 = Bs + w*1024;
  u16* Bl1 = Bs + w*1024 + 512;
  const int fr = lane&15, fq = lane>>4;
  for (int k0=0;k0<K;k0+=32){
    __syncthreads();
    gload16(Ag0+k0, Al0); gload16(Ag1+k0, Al1);
    gload16(Bg0+k0, Bl0); gload16(Bg1+k0, Bl1);
    __syncthreads();
    short8 af[4], bf[4];
    #pragma unroll
    for (int f=0;f<4;f++) af[f] = *(const short8*)&As[(wr + f*16 + fr)*32 + fq*8];
    #pragma unroll
    for (int f=0;f<4;f++) bf[f] = *(const short8*)&Bs[(wc + f*16 + fr)*32 + fq*8];
    #pragma unroll
    for (int i=0;i<4;i++)
      #pragma unroll
      for (int j=0;j<4;j++)
        acc[i][j] = __builtin_amdgcn_mfma_f32_16x16x32_bf16(af[i], bf[j], acc[i][j], 0,0,0);
  }
  const int r0 = fq*4, c0 = fr;
  #pragma unroll
  for (int i=0;i<4;i++)
    #pragma unroll
    for (int j=0;j<4;j++){
      int col = n0 + wc + j*16 + c0;
      float bc = bias[col];
      #pragma unroll
      for (int r=0;r<4;r++){
        int row = m0 + wr + i*16 + r0 + r;
        Cptr[(size_t)row*Nc + col] = acc[i][j][r] + bc;
      }
    }
}

// ===== flash attention: qkv bf16 [8192][1536] -> attn bf16 [8192][512] =====
__global__ __launch_bounds__(256) void k_attn(const u16* __restrict__ qkv, u16* __restrict__ attn){
  const int qt = blockIdx.x, h = blockIdx.y, b = blockIdx.z;
  const int t = threadIdx.x, lane = t & 63, w = t >> 6;
  __shared__ u16 Qs[64][72], Ks[64][72], Vs[64][72], Ps[64][72];
  {
    int r = t >> 2, cc = (t & 3) * 16;
    const u16* src = qkv + ((size_t)(b*Mn + qt*64 + r))*1536 + h*DHn + cc;
    uint4 v0 = *(const uint4*)src;
    uint4 v1 = *(const uint4*)(src + 8);
    *(uint4*)&Qs[r][cc] = v0;
    *(uint4*)&Qs[r][cc+8] = v1;
  }
  __syncthreads();
  const int wr = w*16;
  short8 aq[2];
  aq[0] = *(const short8*)&Qs[wr + (lane&15)][(lane>>4)*8];
  aq[1] = *(const short8*)&Qs[wr + (lane&15)][32 + (lane>>4)*8];
  f32x4 o[4];
  float m_run[4], l_run[4];
  #pragma unroll
  for (int c=0;c<4;c++) o[c] = (f32x4){0.f,0.f,0.f,0.f};
  #pragma unroll
  for (int r=0;r<4;r++){ m_run[r] = -1e30f; l_run[r] = 0.f; }

  for (int kt=0; kt<8; ++kt){
    __syncthreads();
    {
      int r = t >> 2, cc = (t&3)*16;
      const u16* srcK = qkv + ((size_t)(b*Mn + kt*64 + r))*1536 + Hn + h*DHn + cc;
      uint4 kk0 = *(const uint4*)srcK, kk1 = *(const uint4*)(srcK+8);
      *(uint4*)&Ks[r][cc] = kk0; *(uint4*)&Ks[r][cc+8] = kk1;
      const u16* srcV = qkv + ((size_t)(b*Mn + kt*64 + r))*1536 + 2*Hn + h*DHn + cc;
      uint4 vv0 = *(const uint4*)srcV, vv1 = *(const uint4*)(srcV+8);
      u16 tmp[16];
      *(uint4*)tmp = vv0; *(uint4*)(tmp+8) = vv1;
      #pragma unroll
      for (int j=0;j<16;j++) Vs[cc+j][r] = tmp[j];
    }
    __syncthreads();
    f32x4 s[4];
    #pragma unroll
    for (int ct=0;ct<4;ct++){
      s[ct] = (f32x4){0.f,0.f,0.f,0.f};
      short8 bk0 = *(const short8*)&Ks[ct*16 + (lane&15)][(lane>>4)*8];
      short8 bk1 = *(const short8*)&Ks[ct*16 + (lane&15)][32+(lane>>4)*8];
      s[ct] = __builtin_amdgcn_mfma_f32_16x16x32_bf16(aq[0], bk0, s[ct], 0,0,0);
      s[ct] = __builtin_amdgcn_mfma_f32_16x16x32_bf16(aq[1], bk1, s[ct], 0,0,0);
      s[ct] = s[ct] * 0.125f;
    }
    float mx[4];
    #pragma unroll
    for (int r=0;r<4;r++) mx[r] = fmaxf(fmaxf(s[0][r], s[1][r]), fmaxf(s[2][r], s[3][r]));
    #pragma unroll
    for (int off=1; off<16; off<<=1)
      #pragma unroll
      for (int r=0;r<4;r++) mx[r] = fmaxf(mx[r], __shfl_xor(mx[r], off));
    float al[4];
    #pragma unroll
    for (int r=0;r<4;r++){
      float mn = fmaxf(m_run[r], mx[r]);
      al[r] = __expf(m_run[r] - mn);
      m_run[r] = mn;
    }
    float rsum[4] = {0.f,0.f,0.f,0.f};
    #pragma unroll
    for (int ct=0;ct<4;ct++)
      #pragma unroll
      for (int r=0;r<4;r++){
        float p = __expf(s[ct][r] - m_run[r]);
        s[ct][r] = p;
        rsum[r] += p;
      }
    #pragma unroll
    for (int off=1; off<16; off<<=1)
      #pragma unroll
      for (int r=0;r<4;r++) rsum[r] += __shfl_xor(rsum[r], off);
    #pragma unroll
    for (int r=0;r<4;r++) l_run[r] = l_run[r]*al[r] + rsum[r];
    #pragma unroll
    for (int ct=0;ct<4;ct++)
      #pragma unroll
      for (int r=0;r<4;r++) o[ct][r] *= al[r];
    #pragma unroll
    for (int ct=0;ct<4;ct++)
      #pragma unroll
      for (int r=0;r<4;r++)
        Ps[wr + (lane>>4)*4 + r][ct*16 + (lane&15)] = f2bf(s[ct][r]);
    __syncthreads();
    #pragma unroll
    for (int ct=0;ct<4;ct++)
      #pragma unroll
      for (int ks=0;ks<2;ks++){
        short8 ap = *(const short8*)&Ps[wr + (lane&15)][ks*32 + (lane>>4)*8];
        short8 bv = *(const short8*)&Vs[ct*16 + (lane&15)][ks*32 + (lane>>4)*8];
        o[ct] = __builtin_amdgcn_mfma_f32_16x16x32_bf16(ap, bv, o[ct], 0,0,0);
      }
  }
  float inv[4];
  #pragma unroll
  for (int r=0;r<4;r++) inv[r] = 1.0f / l_run[r];
  #pragma unroll
  for (int ct=0;ct<4;ct++)
    #pragma unroll
    for (int r=0;r<4;r++){
      int grow = b*Mn + qt*64 + wr + (lane>>4)*4 + r;
      int gcol = h*DHn + ct*16 + (lane&15);
      attn[(size_t)grow*Hn + gcol] = f2bf(o[ct][r]*inv[r]);
    }
}

// ===== selected-rows-only epilogue: out[b,idx] = tokens[b,idx] + gate*LN(tok+proj) =====
__global__ __launch_bounds__(256) void k_final_sel(const float* __restrict__ tokens,
    const float* __restrict__ proj, const int* __restrict__ sal_idx,
    const float* __restrict__ gate, const float* __restrict__ rg, const float* __restrict__ rb,
    float* __restrict__ out){
  const int wv = threadIdx.x >> 6, lane = threadIdx.x & 63;
  const int r = blockIdx.x*4 + wv;   // 0..8191 (b*512+slot)
  const int b = r >> 9;
  const int idx = sal_idx[r];
  const size_t tbase = ((size_t)b*Nn + idx)*Hn + lane*8;
  float4 t0 = *(const float4*)(tokens+tbase);
  float4 t1 = *(const float4*)(tokens+tbase+4);
  const float* pr = proj + (size_t)r*Hn + lane*8;
  float4 p0 = *(const float4*)pr, p1 = *(const float4*)(pr+4);
  float tv[8] = {t0.x,t0.y,t0.z,t0.w,t1.x,t1.y,t1.z,t1.w};
  float pv[8] = {p0.x,p0.y,p0.z,p0.w,p1.x,p1.y,p1.z,p1.w};
  float sv[8];
  float sx=0.f, sxx=0.f;
  #pragma unroll
  for (int j=0;j<8;j++){ sv[j] = tv[j] + pv[j]; sx += sv[j]; sxx += sv[j]*sv[j]; }
  #pragma unroll
  for (int off=32; off; off>>=1){ sx += __shfl_xor(sx,off); sxx += __shfl_xor(sxx,off); }
  float m = sx*(1.f/Hn), v = sxx*(1.f/Hn) - m*m;
  float rs = rsqrtf(v + 1e-5f);
  int h = lane*8;
  float4 G0 = *(const float4*)(rg+h), G1 = *(const float4*)(rg+h+4);
  float4 B0 = *(const float4*)(rb+h), B1 = *(const float4*)(rb+h+4);
  float gg[8]={G0.x,G0.y,G0.z,G0.w,G1.x,G1.y,G1.z,G1.w};
  float bb[8]={B0.x,B0.y,B0.z,B0.w,B1.x,B1.y,B1.z,B1.w};
  float gt = gate[b];
  float ov[8];
  #pragma unroll
  for (int j=0;j<8;j++) ov[j] = tv[j] + gt * ((sv[j]-m)*rs*gg[j] + bb[j]);
  float4 o0 = {ov[0],ov[1],ov[2],ov[3]};
  float4 o1 = {ov[4],ov[5],ov[6],ov[7]};
  *(float4*)(out+tbase) = o0;
  *(float4*)(out+tbase+4) = o1;
}

// ---------------- workspace layout (bytes) ----------------
#define OFF_GATE    ((size_t)32768)        // 64 -> 256
#define OFF_SAL     ((size_t)33280)        // 65536*4 = 262144
#define OFF_IDX     ((size_t)295424)       // 8192*4 = 32768
#define OFF_WIN     ((size_t)8978944)      // 1536*512*2 = 1572864
#define OFF_WOUT    ((size_t)10551808)     // 512*512*2 = 524288
#define OFF_QKV     ((size_t)11076096)     // 8192*1536*2 = 25165824
#define OFF_ATTN    ((size_t)36241920)     // 8192*512*2 = 8388608
#define OFF_PROJ    ((size_t)44630528)     // 8192*512*4 = 16777216  (end ~61.4MB)
#define OFF_PPART   OFF_PROJ               // 1MB; dead before gemm_out writes proj

extern "C" void kernel_launch(void* const* d_in, const int* in_sizes, int n_in,
                              void* d_out, int out_size, void* d_ws, size_t ws_size,
                              hipStream_t stream) {
  const float* tokens    = (const float*)d_in[0];
  const float* gate_ln_g = (const float*)d_in[1];
  const float* gate_ln_b = (const float*)d_in[2];
  const float* gate_w    = (const float*)d_in[3];
  const float* gate_b    = (const float*)d_in[4];
  const float* sal_ln_g  = (const float*)d_in[5];
  const float* sal_ln_b  = (const float*)d_in[6];
  const float* sal_w     = (const float*)d_in[7];
  const float* sal_b     = (const float*)d_in[8];
  const float* in_proj_w = (const float*)d_in[9];
  const float* in_proj_b = (const float*)d_in[10];
  const float* out_proj_w= (const float*)d_in[11];
  const float* out_proj_b= (const float*)d_in[12];
  const float* rel_ln_g  = (const float*)d_in[13];
  const float* rel_ln_b  = (const float*)d_in[14];
  float* out = (float*)d_out;
  char* ws = (char*)d_ws;

  float* gate    = (float*)(ws + OFF_GATE);
  float* sal     = (float*)(ws + OFF_SAL);
  int*   sal_idx = (int*)  (ws + OFF_IDX);
  u16*   w_in_b  = (u16*)  (ws + OFF_WIN);
  u16*   w_out_b = (u16*)  (ws + OFF_WOUT);
  u16*   qkv     = (u16*)  (ws + OFF_QKV);
  u16*   attnb   = (u16*)  (ws + OFF_ATTN);
  float* proj    = (float*)(ws + OFF_PROJ);
  float* ppart   = (float*)(ws + OFF_PPART);

  // mega prep: weights->bf16, salience, pooled partials, out = tokens
  k_salpool<<<Bn*32, 256, 0, stream>>>(tokens, sal_ln_g, sal_ln_b, sal_w, sal_b,
                                       in_proj_w, out_proj_w, w_in_b, w_out_b,
                                       sal, ppart, out);
  k_topkgate<<<Bn, 1024, 0, stream>>>(sal, sal_idx, ppart, gate_ln_g, gate_ln_b,
                                      gate_w, gate_b, gate);
  // qkv = gather(tokens)@Win^T + b : M=8192, N=1536, K=512 (gather fused, pipelined)
  k_gemm_qkv<<<dim3(12, 64), 256, 0, stream>>>(tokens, sal_idx, w_in_b, in_proj_b, qkv);
  k_attn<<<dim3(8, NHn, Bn), 256, 0, stream>>>(qkv, attnb);
  // proj = attn @ out_proj_w^T + b : M=8192, N=512, K=512
  k_gemm_out<<<dim3(4, 64), 256, 0, stream>>>(attnb, w_out_b, out_proj_b, proj, Bn*Mn, Hn, Hn);
  // update only selected rows
  k_final_sel<<<(Bn*Mn)/4, 256, 0, stream>>>(tokens, proj, sal_idx, gate, rel_ln_g, rel_ln_b, out);
}